// Round 9
// baseline (225.317 us; speedup 1.0000x reference)
//
#include <hip/hip_runtime.h>
#include <hip/hip_fp16.h>
#include <math.h>

#define N_NODES 100000
#define N_EDGES 1600000
#define NBUCK   1563          // ceil(100000/64) buckets of 64 dst nodes
#define NBUCK_P 1568          // padded row length for hist tables
#define NB_HIST 256           // hist blocks (slice 6250)
#define NB_BIN  256           // bin blocks (slice 6250, same rows as hist)

// ws layout (bytes)
#define OFF_BTOT   0x1000u     // int[NBUCK_P] bucket totals
#define OFF_BBASE  0x5000u     // int[NBUCK+1] scan of totals (dump base, exact)
#define OFF_CNT    0x70000u    // int[N_NODES] in-degree (global atomics)
#define OFF_HS     0x780000u   // __half[N_NODES*128] (25.6 MB)
#define OFF_WT     0x2100000u  // __half[128*128] fp16 W1^T (32 KB)
#define OFF_GHIST  0x3980000u  // int[NB_HIST*NBUCK_P]  (1.6 MB)
#define OFF_GCHOFF 0x3B10000u  // int[NB_BIN*NBUCK_P]   (1.6 MB)
#define OFF_DUMP   0x3CA0000u  // int[N_EDGES] packed (6.4 MB, ends 0x42C0000)
#define OFF_ACC    0x4400000u  // __half[N_NODES*128] (25.6 MB, ends 0x5C80000)

typedef _Float16 half8_t __attribute__((ext_vector_type(8)));
typedef float f32x4_t __attribute__((ext_vector_type(4)));

// W1 (f32 [128k][128n]) -> Wt (fp16 [128n][128k]); block b owns k rows [8b,8b+8)
__global__ __launch_bounds__(256) void k_wt(const float* __restrict__ W,
                                            __half* __restrict__ Wt) {
  __shared__ float buf[1024];
  const int t = threadIdx.x;
  const int b = blockIdx.x;
  float4 v = ((const float4*)(W + (size_t)b * 1024))[t];
  *(float4*)&buf[t * 4] = v;
  __syncthreads();
  if (t < 128) {
    union { __half h[8]; int4 v; } u;
#pragma unroll
    for (int k = 0; k < 8; ++k) u.h[k] = __float2half(buf[k * 128 + t]);
    *(int4*)&Wt[(size_t)t * 128 + b * 8] = u.v;
  }
}

// per-block bucket histogram of dst; inline dtype detect; zero cnt slice
__global__ __launch_bounds__(256) void k_hist(const int* __restrict__ p32,
                                              int* __restrict__ G_hist,
                                              int* __restrict__ cnt) {
  __shared__ int hist[NBUCK];
  __shared__ int nz;
  const int t = threadIdx.x;
  if (t == 0) nz = 0;
  for (int i = t; i < NBUCK; i += 256) hist[i] = 0;
  const int zb = blockIdx.x * 391;  // 256*391 >= N_NODES
  for (int i = t; i < 391; i += 256) {
    int idx = zb + i;
    if (idx < N_NODES) cnt[idx] = 0;
  }
  __syncthreads();
  if (p32[2 * t + 1] != 0) atomicAdd(&nz, 1);
  __syncthreads();
  const int s = (nz == 0) ? 1 : 0;  // 1 => int64 (stride 2)
  const int base = blockIdx.x * 6250;
  for (int i = 0; i < 25; ++i) {
    int e = base + i * 256 + t;
    if (e < base + 6250) {
      int c = p32[((size_t)(N_EDGES + e)) << s];
      atomicAdd(&hist[c >> 6], 1);
    }
  }
  __syncthreads();
  for (int i = t; i < NBUCK; i += 256) G_hist[blockIdx.x * NBUCK_P + i] = hist[i];
}

// per bucket: scan 256 exact chunk sizes -> per-binblock offsets + total
__global__ __launch_bounds__(256) void k_bucket_scan(const int* __restrict__ G_hist,
                                                     int* __restrict__ G_choff,
                                                     int* __restrict__ btot) {
  __shared__ int wsum[4];
  const int t = threadIdx.x;
  const int b = blockIdx.x;
  const int c = G_hist[t * NBUCK_P + b];
  int sv = c;
  const int lane = t & 63;
  for (int d = 1; d < 64; d <<= 1) {
    int a = __shfl_up(sv, d);
    if (lane >= d) sv += a;
  }
  if (lane == 63) wsum[t >> 6] = sv;
  __syncthreads();
  int o = 0;
  for (int w2 = 0; w2 < (t >> 6); ++w2) o += wsum[w2];
  G_choff[t * NBUCK_P + b] = o + sv - c;  // exclusive offset within bucket
  if (t == 255) btot[b] = o + sv;
}

// scan 1563 totals -> bbase[0..NBUCK] (exclusive), 1 block
__global__ __launch_bounds__(1024) void k_scan_tot(const int* __restrict__ tot,
                                                   int* __restrict__ base) {
  __shared__ int sm[1024];
  const int t = threadIdx.x;
  int a = (2 * t < NBUCK) ? tot[2 * t] : 0;
  int bb = (2 * t + 1 < NBUCK) ? tot[2 * t + 1] : 0;
  int pair = a + bb;
  sm[t] = pair;
  __syncthreads();
  for (int off = 1; off < 1024; off <<= 1) {
    int x = (t >= off) ? sm[t - off] : 0;
    __syncthreads();
    sm[t] += x;
    __syncthreads();
  }
  int S = sm[t];
  if (2 * t <= NBUCK) base[2 * t] = S - pair;
  if (2 * t + 1 <= NBUCK) base[2 * t + 1] = S - bb;
}

// place packed (src<<6|ldst) records into block-private chunks; global deg atomics
__global__ __launch_bounds__(512) void k_bin(const int* __restrict__ p32,
                                             const int* __restrict__ bbase,
                                             const int* __restrict__ G_choff,
                                             int* __restrict__ dump,
                                             int* __restrict__ cnt) {
  __shared__ int gb[NBUCK];
  __shared__ int cur[NBUCK];
  __shared__ int nz;
  const int t = threadIdx.x;
  const int blk = blockIdx.x;
  if (t == 0) nz = 0;
  for (int i = t; i < NBUCK; i += 512) {
    gb[i] = bbase[i] + G_choff[blk * NBUCK_P + i];
    cur[i] = 0;
  }
  __syncthreads();
  if (t < 256 && p32[2 * t + 1] != 0) atomicAdd(&nz, 1);
  __syncthreads();
  const int s = (nz == 0) ? 1 : 0;
  const int base = blk * 6250;
  for (int i = 0; i < 13; ++i) {
    int e = base + i * 512 + t;
    if (e < base + 6250) {
      int r = p32[((size_t)e) << s];
      int c = p32[((size_t)(N_EDGES + e)) << s];
      int bk = c >> 6;
      atomicAdd(&cnt[c], 1);
      int p = atomicAdd(&cur[bk], 1);
      dump[gb[bk] + p] = (r << 6) | (c & 63);
    }
  }
}

// hs[n] = fp16( rsqrt(cnt[n]+1) * (x @ W1)[n] )  via MFMA f16
__global__ __launch_bounds__(256, 3) void k_gemm1(
    const float* __restrict__ x, const __half* __restrict__ Wt,
    const int* __restrict__ cnt, __half* __restrict__ hs) {
  __shared__ _Float16 xt[64 * 136];
  __shared__ _Float16 wt[128 * 136];
  const int t = threadIdx.x;
  const int row0 = blockIdx.x * 64;
#pragma unroll
  for (int i = 0; i < 8; ++i) {
    int lin = i * 256 + t;
    int r = lin >> 5, c4 = lin & 31;
    int gr = row0 + r;
    float4 v = make_float4(0.f, 0.f, 0.f, 0.f);
    if (gr < N_NODES) v = *(const float4*)(x + (size_t)gr * 128 + c4 * 4);
    union { __half2 h2[2]; int2 iv; } u;
    u.h2[0] = __floats2half2_rn(v.x, v.y);
    u.h2[1] = __floats2half2_rn(v.z, v.w);
    *(int2*)&xt[r * 136 + c4 * 4] = u.iv;
  }
#pragma unroll
  for (int i = 0; i < 8; ++i) {
    int lin = i * 256 + t;
    int n = lin >> 4, kb = lin & 15;
    int4 v = *(const int4*)(Wt + (size_t)n * 128 + kb * 8);
    *(int4*)&wt[n * 136 + kb * 8] = v;
  }
  __syncthreads();

  const int w = t >> 6, l = t & 63;
  const int r = l & 15, g = l >> 4;
  const _Float16* ap = &xt[(w * 16 + r) * 136 + g * 8];
  half8_t af[4];
#pragma unroll
  for (int ks = 0; ks < 4; ++ks) af[ks] = *(const half8_t*)&ap[ks * 32];

  const int rbase = row0 + w * 16 + g * 4;
  float dv[4];
#pragma unroll
  for (int j = 0; j < 4; ++j) {
    int rr = rbase + j;
    dv[j] = (rr < N_NODES) ? rsqrtf((float)cnt[rr] + 1.0f) : 0.f;
  }

#pragma unroll
  for (int ct = 0; ct < 8; ++ct) {
    f32x4_t acc = {0.f, 0.f, 0.f, 0.f};
    const _Float16* bp = &wt[(ct * 16 + r) * 136 + g * 8];
#pragma unroll
    for (int ks = 0; ks < 4; ++ks) {
      half8_t bf = *(const half8_t*)&bp[ks * 32];
      acc = __builtin_amdgcn_mfma_f32_16x16x32_f16(af[ks], bf, acc, 0, 0, 0);
    }
#pragma unroll
    for (int j = 0; j < 4; ++j) {
      int rr = rbase + j;
      if (rr < N_NODES)
        hs[(size_t)rr * 128 + ct * 16 + r] = __float2half(acc[j] * dv[j]);
    }
  }
}

// fused CSR-placement + aggregation per bucket (64 nodes, 512 threads).
// acc[n] = fp16( dis[n]*(hs[n] + sum_in hs[src]) + b1 ), dis = rsqrt(cnt+1)
__global__ __launch_bounds__(512) void k_aggcsr(
    const __half* __restrict__ hs, const int* __restrict__ dump,
    const int* __restrict__ bbase, const int* __restrict__ cnt,
    const float* __restrict__ b1, __half* __restrict__ acc) {
  __shared__ int stage[3072];
  __shared__ int cnt_s[64];
  __shared__ int off_s[64];
  __shared__ int cur_s[64];
  const int t = threadIdx.x;
  const int b = blockIdx.x;
  const int n0 = b << 6;
  if (t < 64) {
    int n = n0 + t;
    int v = (n < N_NODES) ? cnt[n] : 0;
    cnt_s[t] = v;
    int sv = v;
    for (int d = 1; d < 64; d <<= 1) {
      int u = __shfl_up(sv, d);
      if (t >= d) sv += u;
    }
    off_s[t] = sv - v;
    cur_s[t] = sv - v;
  }
  __syncthreads();
  const int rb = bbase[b];
  const int m = bbase[b + 1] - rb;
  for (int j = t; j < m; j += 512) {
    int rec = dump[rb + j];
    int p = atomicAdd(&cur_s[rec & 63], 1);
    stage[p] = rec >> 6;
  }
  __syncthreads();

  const int hw = t >> 5, lane = t & 31;
  for (int i = hw; i < 64; i += 16) {
    int n = n0 + i;
    if (n >= N_NODES) continue;
    float4 sum;
    {
      uint2 raw = *(const uint2*)(hs + (size_t)n * 128 + lane * 4);  // self-loop
      float2 fa = __half22float2(*(__half2*)&raw.x);
      float2 fb = __half22float2(*(__half2*)&raw.y);
      sum = make_float4(fa.x, fa.y, fb.x, fb.y);
    }
    int j = off_s[i];
    const int e0 = off_s[i] + cnt_s[i];
    for (; j + 8 <= e0; j += 8) {
      uint2 r[8];
#pragma unroll
      for (int q = 0; q < 8; ++q) {
        int src = stage[j + q];
        r[q] = *(const uint2*)(hs + (size_t)src * 128 + lane * 4);
      }
#pragma unroll
      for (int q = 0; q < 8; ++q) {
        float2 a = __half22float2(*(__half2*)&r[q].x);
        float2 bf = __half22float2(*(__half2*)&r[q].y);
        sum.x += a.x; sum.y += a.y; sum.z += bf.x; sum.w += bf.y;
      }
    }
    if (j + 4 <= e0) {
      uint2 r[4];
#pragma unroll
      for (int q = 0; q < 4; ++q) {
        int src = stage[j + q];
        r[q] = *(const uint2*)(hs + (size_t)src * 128 + lane * 4);
      }
#pragma unroll
      for (int q = 0; q < 4; ++q) {
        float2 a = __half22float2(*(__half2*)&r[q].x);
        float2 bf = __half22float2(*(__half2*)&r[q].y);
        sum.x += a.x; sum.y += a.y; sum.z += bf.x; sum.w += bf.y;
      }
      j += 4;
    }
    for (; j < e0; ++j) {
      int src = stage[j];
      uint2 r0 = *(const uint2*)(hs + (size_t)src * 128 + lane * 4);
      float2 a0 = __half22float2(*(__half2*)&r0.x);
      float2 b0 = __half22float2(*(__half2*)&r0.y);
      sum.x += a0.x; sum.y += a0.y; sum.z += b0.x; sum.w += b0.y;
    }
    float d = rsqrtf((float)cnt_s[i] + 1.0f);
    float4 bb = *(const float4*)(b1 + lane * 4);
    union { __half2 h[2]; unsigned long long v; } u;
    u.h[0] = __floats2half2_rn(fmaf(d, sum.x, bb.x), fmaf(d, sum.y, bb.y));
    u.h[1] = __floats2half2_rn(fmaf(d, sum.z, bb.z), fmaf(d, sum.w, bb.w));
    __builtin_nontemporal_store(
        u.v, (unsigned long long*)(acc + (size_t)n * 128 + lane * 4));
  }
}

// out[n] = log_softmax(relu(acc[n]) @ linW + linb)   -- 4 lanes/node
__global__ __launch_bounds__(256) void k_final(
    const __half* __restrict__ acc, const float* __restrict__ linW,
    const float* __restrict__ linb, float* __restrict__ out) {
  __shared__ float vs[64][132];
  __shared__ float wl[128 * 40];
  __shared__ float lb[40];
  const int t = threadIdx.x;
  const int n0 = blockIdx.x * 64;
#pragma unroll
  for (int i = 0; i < 5; ++i) {
    int lin = i * 256 + t;
    ((float4*)wl)[lin] = ((const float4*)linW)[lin];
  }
  if (t < 40) lb[t] = linb[t];
#pragma unroll
  for (int i = 0; i < 4; ++i) {
    int lin = i * 256 + t;
    int r = lin >> 4, c8 = lin & 15;
    int n = n0 + r;
    float vals[8];
#pragma unroll
    for (int q = 0; q < 8; ++q) vals[q] = 0.f;
    if (n < N_NODES) {
      uint4 raw = *(const uint4*)(acc + (size_t)n * 128 + c8 * 8);
      const __half2* hp = (const __half2*)&raw;
#pragma unroll
      for (int q = 0; q < 4; ++q) {
        float2 f = __half22float2(hp[q]);
        vals[2 * q]     = fmaxf(f.x, 0.f);
        vals[2 * q + 1] = fmaxf(f.y, 0.f);
      }
    }
#pragma unroll
    for (int q = 0; q < 8; ++q) vs[r][c8 * 8 + q] = vals[q];
  }
  __syncthreads();
  const int nl = t >> 2, l4 = t & 3;
  const int n = n0 + nl;
  if (n >= N_NODES) return;
  float lg[10];
#pragma unroll
  for (int j = 0; j < 10; ++j) lg[j] = lb[l4 * 10 + j];
  for (int k = 0; k < 128; ++k) {
    float vk = vs[nl][k];
#pragma unroll
    for (int j = 0; j < 10; ++j) lg[j] = fmaf(vk, wl[k * 40 + l4 * 10 + j], lg[j]);
  }
  float m = lg[0];
#pragma unroll
  for (int j = 1; j < 10; ++j) m = fmaxf(m, lg[j]);
  m = fmaxf(m, __shfl_xor(m, 1));
  m = fmaxf(m, __shfl_xor(m, 2));
  float s = 0.f;
#pragma unroll
  for (int j = 0; j < 10; ++j) s += expf(lg[j] - m);
  s += __shfl_xor(s, 1);
  s += __shfl_xor(s, 2);
  float lse = m + logf(s);
#pragma unroll
  for (int j = 0; j < 10; ++j) out[(size_t)n * 40 + l4 * 10 + j] = lg[j] - lse;
}

extern "C" void kernel_launch(void* const* d_in, const int* in_sizes, int n_in,
                              void* d_out, int out_size, void* d_ws, size_t ws_size,
                              hipStream_t stream) {
  const float* x    = (const float*)d_in[0];
  const int*   ei   = (const int*)d_in[1];
  const float* W1   = (const float*)d_in[2];
  const float* b1   = (const float*)d_in[3];
  const float* linW = (const float*)d_in[4];
  const float* linb = (const float*)d_in[5];
  float* out = (float*)d_out;
  char* ws = (char*)d_ws;

  int*    btot   = (int*)(ws + OFF_BTOT);
  int*    bbase  = (int*)(ws + OFF_BBASE);
  int*    cnt    = (int*)(ws + OFF_CNT);
  __half* hs     = (__half*)(ws + OFF_HS);
  __half* Wt     = (__half*)(ws + OFF_WT);
  int*    ghist  = (int*)(ws + OFF_GHIST);
  int*    gchoff = (int*)(ws + OFF_GCHOFF);
  int*    dump   = (int*)(ws + OFF_DUMP);
  __half* acc    = (__half*)(ws + OFF_ACC);

  k_wt<<<16, 256, 0, stream>>>(W1, Wt);
  k_hist<<<NB_HIST, 256, 0, stream>>>(ei, ghist, cnt);
  k_bucket_scan<<<NBUCK, 256, 0, stream>>>(ghist, gchoff, btot);
  k_scan_tot<<<1, 1024, 0, stream>>>(btot, bbase);
  k_bin<<<NB_BIN, 512, 0, stream>>>(ei, bbase, gchoff, dump, cnt);
  k_gemm1<<<NBUCK, 256, 0, stream>>>(x, Wt, cnt, hs);
  k_aggcsr<<<NBUCK, 512, 0, stream>>>(hs, dump, bbase, cnt, b1, acc);
  k_final<<<NBUCK, 256, 0, stream>>>(acc, linW, linb, out);
}

// Round 10
// 178.487 us; speedup vs baseline: 1.2624x; 1.2624x over previous
//
#include <hip/hip_runtime.h>
#include <hip/hip_fp16.h>
#include <math.h>

#define N_NODES 100000
#define N_EDGES 1600000
#define NBUCK   1563          // ceil(100000/64) buckets of 64 dst nodes
#define NBUCK_P 1568          // padded row length for hist tables
#define NB_HIST 256           // hist blocks (slice 6250)
#define NB_BIN  256           // bin blocks (slice 6250, same rows as hist)

// ws layout (bytes)
#define OFF_BTOT   0x1000u     // int[NBUCK_P] bucket totals
#define OFF_BBASE  0x5000u     // int[NBUCK+1] scan of totals (dump base, exact)
#define OFF_CNT    0x70000u    // int[N_NODES] in-degree (written once by k_deg)
#define OFF_HS     0x780000u   // __half[N_NODES*128] (25.6 MB)
#define OFF_WT     0x2100000u  // __half[128*128] fp16 W1^T (32 KB)
#define OFF_GHIST  0x3980000u  // int[NB_HIST*NBUCK_P]  (1.6 MB)
#define OFF_GCHOFF 0x3B10000u  // int[NB_BIN*NBUCK_P]   (1.6 MB)
#define OFF_DUMP   0x3CA0000u  // int[N_EDGES] packed (6.4 MB, ends 0x42C0000)
#define OFF_ACC    0x4400000u  // __half[N_NODES*128] (25.6 MB, ends 0x5C80000)

typedef _Float16 half8_t __attribute__((ext_vector_type(8)));
typedef float f32x4_t __attribute__((ext_vector_type(4)));

// W1 (f32 [128k][128n]) -> Wt (fp16 [128n][128k]); block b owns k rows [8b,8b+8)
__global__ __launch_bounds__(256) void k_wt(const float* __restrict__ W,
                                            __half* __restrict__ Wt) {
  __shared__ float buf[1024];
  const int t = threadIdx.x;
  const int b = blockIdx.x;
  float4 v = ((const float4*)(W + (size_t)b * 1024))[t];
  *(float4*)&buf[t * 4] = v;
  __syncthreads();
  if (t < 128) {
    union { __half h[8]; int4 v; } u;
#pragma unroll
    for (int k = 0; k < 8; ++k) u.h[k] = __float2half(buf[k * 128 + t]);
    *(int4*)&Wt[(size_t)t * 128 + b * 8] = u.v;
  }
}

// per-block bucket histogram of dst; inline dtype detect
__global__ __launch_bounds__(256) void k_hist(const int* __restrict__ p32,
                                              int* __restrict__ G_hist) {
  __shared__ int hist[NBUCK];
  __shared__ int nz;
  const int t = threadIdx.x;
  if (t == 0) nz = 0;
  for (int i = t; i < NBUCK; i += 256) hist[i] = 0;
  __syncthreads();
  if (p32[2 * t + 1] != 0) atomicAdd(&nz, 1);
  __syncthreads();
  const int s = (nz == 0) ? 1 : 0;  // 1 => int64 (stride 2)
  const int base = blockIdx.x * 6250;
  for (int i = 0; i < 25; ++i) {
    int e = base + i * 256 + t;
    if (e < base + 6250) {
      int c = p32[((size_t)(N_EDGES + e)) << s];
      atomicAdd(&hist[c >> 6], 1);
    }
  }
  __syncthreads();
  for (int i = t; i < NBUCK; i += 256) G_hist[blockIdx.x * NBUCK_P + i] = hist[i];
}

// per bucket: scan 256 exact chunk sizes -> per-binblock offsets + total
__global__ __launch_bounds__(256) void k_bucket_scan(const int* __restrict__ G_hist,
                                                     int* __restrict__ G_choff,
                                                     int* __restrict__ btot) {
  __shared__ int wsum[4];
  const int t = threadIdx.x;
  const int b = blockIdx.x;
  const int c = G_hist[t * NBUCK_P + b];
  int sv = c;
  const int lane = t & 63;
  for (int d = 1; d < 64; d <<= 1) {
    int a = __shfl_up(sv, d);
    if (lane >= d) sv += a;
  }
  if (lane == 63) wsum[t >> 6] = sv;
  __syncthreads();
  int o = 0;
  for (int w2 = 0; w2 < (t >> 6); ++w2) o += wsum[w2];
  G_choff[t * NBUCK_P + b] = o + sv - c;  // exclusive offset within bucket
  if (t == 255) btot[b] = o + sv;
}

// scan 1563 totals -> bbase[0..NBUCK] (exclusive), 1 block
__global__ __launch_bounds__(1024) void k_scan_tot(const int* __restrict__ tot,
                                                   int* __restrict__ base) {
  __shared__ int sm[1024];
  const int t = threadIdx.x;
  int a = (2 * t < NBUCK) ? tot[2 * t] : 0;
  int bb = (2 * t + 1 < NBUCK) ? tot[2 * t + 1] : 0;
  int pair = a + bb;
  sm[t] = pair;
  __syncthreads();
  for (int off = 1; off < 1024; off <<= 1) {
    int x = (t >= off) ? sm[t - off] : 0;
    __syncthreads();
    sm[t] += x;
    __syncthreads();
  }
  int S = sm[t];
  if (2 * t <= NBUCK) base[2 * t] = S - pair;
  if (2 * t + 1 <= NBUCK) base[2 * t + 1] = S - bb;
}

// place packed (src<<6|ldst) records into block-private chunks (no global atomics)
__global__ __launch_bounds__(512) void k_bin(const int* __restrict__ p32,
                                             const int* __restrict__ bbase,
                                             const int* __restrict__ G_choff,
                                             int* __restrict__ dump) {
  __shared__ int gb[NBUCK];
  __shared__ int cur[NBUCK];
  __shared__ int nz;
  const int t = threadIdx.x;
  const int blk = blockIdx.x;
  if (t == 0) nz = 0;
  for (int i = t; i < NBUCK; i += 512) {
    gb[i] = bbase[i] + G_choff[blk * NBUCK_P + i];
    cur[i] = 0;
  }
  __syncthreads();
  if (t < 256 && p32[2 * t + 1] != 0) atomicAdd(&nz, 1);
  __syncthreads();
  const int s = (nz == 0) ? 1 : 0;
  const int base = blk * 6250;
  for (int i = 0; i < 13; ++i) {
    int e = base + i * 512 + t;
    if (e < base + 6250) {
      int r = p32[((size_t)e) << s];
      int c = p32[((size_t)(N_EDGES + e)) << s];
      int bk = c >> 6;
      int p = atomicAdd(&cur[bk], 1);
      dump[gb[bk] + p] = (r << 6) | (c & 63);
    }
  }
}

// per bucket: degree from dump chunk (LDS counts, one coalesced write)
__global__ __launch_bounds__(256) void k_deg(const int* __restrict__ dump,
                                             const int* __restrict__ bbase,
                                             int* __restrict__ cnt) {
  __shared__ int c_s[64];
  const int t = threadIdx.x;
  const int b = blockIdx.x;
  if (t < 64) c_s[t] = 0;
  __syncthreads();
  const int rb = bbase[b];
  const int m = bbase[b + 1] - rb;
  for (int j = t; j < m; j += 256) atomicAdd(&c_s[dump[rb + j] & 63], 1);
  __syncthreads();
  if (t < 64) {
    int n = (b << 6) + t;
    if (n < N_NODES) cnt[n] = c_s[t];
  }
}

// hs[n] = fp16( rsqrt(cnt[n]+1) * (x @ W1)[n] )  via MFMA f16
__global__ __launch_bounds__(256, 3) void k_gemm1(
    const float* __restrict__ x, const __half* __restrict__ Wt,
    const int* __restrict__ cnt, __half* __restrict__ hs) {
  __shared__ _Float16 xt[64 * 136];
  __shared__ _Float16 wt[128 * 136];
  const int t = threadIdx.x;
  const int row0 = blockIdx.x * 64;
#pragma unroll
  for (int i = 0; i < 8; ++i) {
    int lin = i * 256 + t;
    int r = lin >> 5, c4 = lin & 31;
    int gr = row0 + r;
    float4 v = make_float4(0.f, 0.f, 0.f, 0.f);
    if (gr < N_NODES) v = *(const float4*)(x + (size_t)gr * 128 + c4 * 4);
    union { __half2 h2[2]; int2 iv; } u;
    u.h2[0] = __floats2half2_rn(v.x, v.y);
    u.h2[1] = __floats2half2_rn(v.z, v.w);
    *(int2*)&xt[r * 136 + c4 * 4] = u.iv;
  }
#pragma unroll
  for (int i = 0; i < 8; ++i) {
    int lin = i * 256 + t;
    int n = lin >> 4, kb = lin & 15;
    int4 v = *(const int4*)(Wt + (size_t)n * 128 + kb * 8);
    *(int4*)&wt[n * 136 + kb * 8] = v;
  }
  __syncthreads();

  const int w = t >> 6, l = t & 63;
  const int r = l & 15, g = l >> 4;
  const _Float16* ap = &xt[(w * 16 + r) * 136 + g * 8];
  half8_t af[4];
#pragma unroll
  for (int ks = 0; ks < 4; ++ks) af[ks] = *(const half8_t*)&ap[ks * 32];

  const int rbase = row0 + w * 16 + g * 4;
  float dv[4];
#pragma unroll
  for (int j = 0; j < 4; ++j) {
    int rr = rbase + j;
    dv[j] = (rr < N_NODES) ? rsqrtf((float)cnt[rr] + 1.0f) : 0.f;
  }

#pragma unroll
  for (int ct = 0; ct < 8; ++ct) {
    f32x4_t acc = {0.f, 0.f, 0.f, 0.f};
    const _Float16* bp = &wt[(ct * 16 + r) * 136 + g * 8];
#pragma unroll
    for (int ks = 0; ks < 4; ++ks) {
      half8_t bf = *(const half8_t*)&bp[ks * 32];
      acc = __builtin_amdgcn_mfma_f32_16x16x32_f16(af[ks], bf, acc, 0, 0, 0);
    }
#pragma unroll
    for (int j = 0; j < 4; ++j) {
      int rr = rbase + j;
      if (rr < N_NODES)
        hs[(size_t)rr * 128 + ct * 16 + r] = __float2half(acc[j] * dv[j]);
    }
  }
}

// fused CSR-placement + aggregation per bucket (64 nodes, 512 threads).
// acc[n] = fp16( dis[n]*(hs[n] + sum_in hs[src]) + b1 ), dis = rsqrt(cnt+1)
__global__ __launch_bounds__(512) void k_aggcsr(
    const __half* __restrict__ hs, const int* __restrict__ dump,
    const int* __restrict__ bbase, const int* __restrict__ cnt,
    const float* __restrict__ b1, __half* __restrict__ acc) {
  __shared__ int stage[3072];
  __shared__ int cnt_s[64];
  __shared__ int off_s[64];
  __shared__ int cur_s[64];
  const int t = threadIdx.x;
  const int b = blockIdx.x;
  const int n0 = b << 6;
  if (t < 64) {
    int n = n0 + t;
    int v = (n < N_NODES) ? cnt[n] : 0;
    cnt_s[t] = v;
    int sv = v;
    for (int d = 1; d < 64; d <<= 1) {
      int u = __shfl_up(sv, d);
      if (t >= d) sv += u;
    }
    off_s[t] = sv - v;
    cur_s[t] = sv - v;
  }
  __syncthreads();
  const int rb = bbase[b];
  const int m = bbase[b + 1] - rb;
  for (int j = t; j < m; j += 512) {
    int rec = dump[rb + j];
    int p = atomicAdd(&cur_s[rec & 63], 1);
    stage[p] = rec >> 6;
  }
  __syncthreads();

  const int hw = t >> 5, lane = t & 31;
  for (int i = hw; i < 64; i += 16) {
    int n = n0 + i;
    if (n >= N_NODES) continue;
    float4 sum;
    {
      uint2 raw = *(const uint2*)(hs + (size_t)n * 128 + lane * 4);  // self-loop
      float2 fa = __half22float2(*(__half2*)&raw.x);
      float2 fb = __half22float2(*(__half2*)&raw.y);
      sum = make_float4(fa.x, fa.y, fb.x, fb.y);
    }
    int j = off_s[i];
    const int e0 = off_s[i] + cnt_s[i];
    for (; j + 8 <= e0; j += 8) {
      uint2 r[8];
#pragma unroll
      for (int q = 0; q < 8; ++q) {
        int src = stage[j + q];
        r[q] = *(const uint2*)(hs + (size_t)src * 128 + lane * 4);
      }
#pragma unroll
      for (int q = 0; q < 8; ++q) {
        float2 a = __half22float2(*(__half2*)&r[q].x);
        float2 bf = __half22float2(*(__half2*)&r[q].y);
        sum.x += a.x; sum.y += a.y; sum.z += bf.x; sum.w += bf.y;
      }
    }
    if (j + 4 <= e0) {
      uint2 r[4];
#pragma unroll
      for (int q = 0; q < 4; ++q) {
        int src = stage[j + q];
        r[q] = *(const uint2*)(hs + (size_t)src * 128 + lane * 4);
      }
#pragma unroll
      for (int q = 0; q < 4; ++q) {
        float2 a = __half22float2(*(__half2*)&r[q].x);
        float2 bf = __half22float2(*(__half2*)&r[q].y);
        sum.x += a.x; sum.y += a.y; sum.z += bf.x; sum.w += bf.y;
      }
      j += 4;
    }
    for (; j < e0; ++j) {
      int src = stage[j];
      uint2 r0 = *(const uint2*)(hs + (size_t)src * 128 + lane * 4);
      float2 a0 = __half22float2(*(__half2*)&r0.x);
      float2 b0 = __half22float2(*(__half2*)&r0.y);
      sum.x += a0.x; sum.y += a0.y; sum.z += b0.x; sum.w += b0.y;
    }
    float d = rsqrtf((float)cnt_s[i] + 1.0f);
    float4 bb = *(const float4*)(b1 + lane * 4);
    union { __half2 h[2]; unsigned long long v; } u;
    u.h[0] = __floats2half2_rn(fmaf(d, sum.x, bb.x), fmaf(d, sum.y, bb.y));
    u.h[1] = __floats2half2_rn(fmaf(d, sum.z, bb.z), fmaf(d, sum.w, bb.w));
    __builtin_nontemporal_store(
        u.v, (unsigned long long*)(acc + (size_t)n * 128 + lane * 4));
  }
}

// out[n] = log_softmax(relu(acc[n]) @ linW + linb)   -- 4 lanes/node
__global__ __launch_bounds__(256) void k_final(
    const __half* __restrict__ acc, const float* __restrict__ linW,
    const float* __restrict__ linb, float* __restrict__ out) {
  __shared__ float vs[64][132];
  __shared__ float wl[128 * 40];
  __shared__ float lb[40];
  const int t = threadIdx.x;
  const int n0 = blockIdx.x * 64;
#pragma unroll
  for (int i = 0; i < 5; ++i) {
    int lin = i * 256 + t;
    ((float4*)wl)[lin] = ((const float4*)linW)[lin];
  }
  if (t < 40) lb[t] = linb[t];
#pragma unroll
  for (int i = 0; i < 4; ++i) {
    int lin = i * 256 + t;
    int r = lin >> 4, c8 = lin & 15;
    int n = n0 + r;
    float vals[8];
#pragma unroll
    for (int q = 0; q < 8; ++q) vals[q] = 0.f;
    if (n < N_NODES) {
      uint4 raw = *(const uint4*)(acc + (size_t)n * 128 + c8 * 8);
      const __half2* hp = (const __half2*)&raw;
#pragma unroll
      for (int q = 0; q < 4; ++q) {
        float2 f = __half22float2(hp[q]);
        vals[2 * q]     = fmaxf(f.x, 0.f);
        vals[2 * q + 1] = fmaxf(f.y, 0.f);
      }
    }
#pragma unroll
    for (int q = 0; q < 8; ++q) vs[r][c8 * 8 + q] = vals[q];
  }
  __syncthreads();
  const int nl = t >> 2, l4 = t & 3;
  const int n = n0 + nl;
  if (n >= N_NODES) return;
  float lg[10];
#pragma unroll
  for (int j = 0; j < 10; ++j) lg[j] = lb[l4 * 10 + j];
  for (int k = 0; k < 128; ++k) {
    float vk = vs[nl][k];
#pragma unroll
    for (int j = 0; j < 10; ++j) lg[j] = fmaf(vk, wl[k * 40 + l4 * 10 + j], lg[j]);
  }
  float m = lg[0];
#pragma unroll
  for (int j = 1; j < 10; ++j) m = fmaxf(m, lg[j]);
  m = fmaxf(m, __shfl_xor(m, 1));
  m = fmaxf(m, __shfl_xor(m, 2));
  float s = 0.f;
#pragma unroll
  for (int j = 0; j < 10; ++j) s += expf(lg[j] - m);
  s += __shfl_xor(s, 1);
  s += __shfl_xor(s, 2);
  float lse = m + logf(s);
#pragma unroll
  for (int j = 0; j < 10; ++j) out[(size_t)n * 40 + l4 * 10 + j] = lg[j] - lse;
}

extern "C" void kernel_launch(void* const* d_in, const int* in_sizes, int n_in,
                              void* d_out, int out_size, void* d_ws, size_t ws_size,
                              hipStream_t stream) {
  const float* x    = (const float*)d_in[0];
  const int*   ei   = (const int*)d_in[1];
  const float* W1   = (const float*)d_in[2];
  const float* b1   = (const float*)d_in[3];
  const float* linW = (const float*)d_in[4];
  const float* linb = (const float*)d_in[5];
  float* out = (float*)d_out;
  char* ws = (char*)d_ws;

  int*    btot   = (int*)(ws + OFF_BTOT);
  int*    bbase  = (int*)(ws + OFF_BBASE);
  int*    cnt    = (int*)(ws + OFF_CNT);
  __half* hs     = (__half*)(ws + OFF_HS);
  __half* Wt     = (__half*)(ws + OFF_WT);
  int*    ghist  = (int*)(ws + OFF_GHIST);
  int*    gchoff = (int*)(ws + OFF_GCHOFF);
  int*    dump   = (int*)(ws + OFF_DUMP);
  __half* acc    = (__half*)(ws + OFF_ACC);

  k_wt<<<16, 256, 0, stream>>>(W1, Wt);
  k_hist<<<NB_HIST, 256, 0, stream>>>(ei, ghist);
  k_bucket_scan<<<NBUCK, 256, 0, stream>>>(ghist, gchoff, btot);
  k_scan_tot<<<1, 1024, 0, stream>>>(btot, bbase);
  k_bin<<<NB_BIN, 512, 0, stream>>>(ei, bbase, gchoff, dump);
  k_deg<<<NBUCK, 256, 0, stream>>>(dump, bbase, cnt);
  k_gemm1<<<NBUCK, 256, 0, stream>>>(x, Wt, cnt, hs);
  k_aggcsr<<<NBUCK, 512, 0, stream>>>(hs, dump, bbase, cnt, b1, acc);
  k_final<<<NBUCK, 256, 0, stream>>>(acc, linW, linb, out);
}

// Round 11
// 151.733 us; speedup vs baseline: 1.4850x; 1.1763x over previous
//
#include <hip/hip_runtime.h>
#include <hip/hip_fp16.h>
#include <math.h>

#define N_NODES 100000
#define N_EDGES 1600000
#define NBUCK   1563          // ceil(100000/64) buckets of 64 dst nodes
#define NBUCK_P 1568          // padded row length for hist tables
#define NB_HIST 256           // hist blocks (slice 6250)
#define NB_BIN  256           // bin blocks (slice 6250, same rows as hist)

// ws layout (bytes)
#define OFF_BTOT   0x1000u     // int[NBUCK_P] bucket totals
#define OFF_BBASE  0x5000u     // int[NBUCK+1] scan of totals (dump base, exact)
#define OFF_CNT    0x70000u    // int[N_NODES] in-degree (written once by k_deg)
#define OFF_HS     0x780000u   // __half[N_NODES*128] (25.6 MB)
#define OFF_WT     0x2100000u  // __half[128*128] fp16 W1^T (32 KB)
#define OFF_GHIST  0x3980000u  // int[NB_HIST*NBUCK_P]  (1.6 MB)
#define OFF_GCHOFF 0x3B10000u  // int[NB_BIN*NBUCK_P]   (1.6 MB)
#define OFF_DUMP   0x3CA0000u  // int[N_EDGES] packed (6.4 MB, ends 0x42C0000)

typedef _Float16 half8_t __attribute__((ext_vector_type(8)));
typedef float f32x4_t __attribute__((ext_vector_type(4)));

// hist blocks [0,255]: per-block bucket histogram of dst (inline dtype detect).
// blocks [256,271]: W1 (f32 [128k][128n]) -> Wt fp16 [128n][128k].
__global__ __launch_bounds__(256) void k_hist(const int* __restrict__ p32,
                                              int* __restrict__ G_hist,
                                              const float* __restrict__ W,
                                              __half* __restrict__ Wt) {
  const int t = threadIdx.x;
  if (blockIdx.x >= NB_HIST) {  // ---- wt transpose part ----
    __shared__ float buf[1024];
    const int b = blockIdx.x - NB_HIST;
    float4 v = ((const float4*)(W + (size_t)b * 1024))[t];
    *(float4*)&buf[t * 4] = v;
    __syncthreads();
    if (t < 128) {
      union { __half h[8]; int4 v; } u;
#pragma unroll
      for (int k = 0; k < 8; ++k) u.h[k] = __float2half(buf[k * 128 + t]);
      *(int4*)&Wt[(size_t)t * 128 + b * 8] = u.v;
    }
    return;
  }
  __shared__ int hist[NBUCK];
  __shared__ int nz;
  if (t == 0) nz = 0;
  for (int i = t; i < NBUCK; i += 256) hist[i] = 0;
  __syncthreads();
  if (p32[2 * t + 1] != 0) atomicAdd(&nz, 1);
  __syncthreads();
  const int s = (nz == 0) ? 1 : 0;  // 1 => int64 (stride 2)
  const int base = blockIdx.x * 6250;
  for (int i = 0; i < 25; ++i) {
    int e = base + i * 256 + t;
    if (e < base + 6250) {
      int c = p32[((size_t)(N_EDGES + e)) << s];
      atomicAdd(&hist[c >> 6], 1);
    }
  }
  __syncthreads();
  for (int i = t; i < NBUCK; i += 256) G_hist[blockIdx.x * NBUCK_P + i] = hist[i];
}

// per bucket: scan 256 exact chunk sizes -> per-binblock offsets + total
__global__ __launch_bounds__(256) void k_bucket_scan(const int* __restrict__ G_hist,
                                                     int* __restrict__ G_choff,
                                                     int* __restrict__ btot) {
  __shared__ int wsum[4];
  const int t = threadIdx.x;
  const int b = blockIdx.x;
  const int c = G_hist[t * NBUCK_P + b];
  int sv = c;
  const int lane = t & 63;
  for (int d = 1; d < 64; d <<= 1) {
    int a = __shfl_up(sv, d);
    if (lane >= d) sv += a;
  }
  if (lane == 63) wsum[t >> 6] = sv;
  __syncthreads();
  int o = 0;
  for (int w2 = 0; w2 < (t >> 6); ++w2) o += wsum[w2];
  G_choff[t * NBUCK_P + b] = o + sv - c;  // exclusive offset within bucket
  if (t == 255) btot[b] = o + sv;
}

// scan 1563 totals -> bbase[0..NBUCK] (exclusive), 1 block
__global__ __launch_bounds__(1024) void k_scan_tot(const int* __restrict__ tot,
                                                   int* __restrict__ base) {
  __shared__ int sm[1024];
  const int t = threadIdx.x;
  int a = (2 * t < NBUCK) ? tot[2 * t] : 0;
  int bb = (2 * t + 1 < NBUCK) ? tot[2 * t + 1] : 0;
  int pair = a + bb;
  sm[t] = pair;
  __syncthreads();
  for (int off = 1; off < 1024; off <<= 1) {
    int x = (t >= off) ? sm[t - off] : 0;
    __syncthreads();
    sm[t] += x;
    __syncthreads();
  }
  int S = sm[t];
  if (2 * t <= NBUCK) base[2 * t] = S - pair;
  if (2 * t + 1 <= NBUCK) base[2 * t + 1] = S - bb;
}

// place packed (src<<6|ldst) records into block-private chunks (no global atomics)
__global__ __launch_bounds__(512) void k_bin(const int* __restrict__ p32,
                                             const int* __restrict__ bbase,
                                             const int* __restrict__ G_choff,
                                             int* __restrict__ dump) {
  __shared__ int gb[NBUCK];
  __shared__ int cur[NBUCK];
  __shared__ int nz;
  const int t = threadIdx.x;
  const int blk = blockIdx.x;
  if (t == 0) nz = 0;
  for (int i = t; i < NBUCK; i += 512) {
    gb[i] = bbase[i] + G_choff[blk * NBUCK_P + i];
    cur[i] = 0;
  }
  __syncthreads();
  if (t < 256 && p32[2 * t + 1] != 0) atomicAdd(&nz, 1);
  __syncthreads();
  const int s = (nz == 0) ? 1 : 0;
  const int base = blk * 6250;
  for (int i = 0; i < 13; ++i) {
    int e = base + i * 512 + t;
    if (e < base + 6250) {
      int r = p32[((size_t)e) << s];
      int c = p32[((size_t)(N_EDGES + e)) << s];
      int bk = c >> 6;
      int p = atomicAdd(&cur[bk], 1);
      dump[gb[bk] + p] = (r << 6) | (c & 63);
    }
  }
}

// per bucket: degree from dump chunk (LDS counts, one coalesced write)
__global__ __launch_bounds__(256) void k_deg(const int* __restrict__ dump,
                                             const int* __restrict__ bbase,
                                             int* __restrict__ cnt) {
  __shared__ int c_s[64];
  const int t = threadIdx.x;
  const int b = blockIdx.x;
  if (t < 64) c_s[t] = 0;
  __syncthreads();
  const int rb = bbase[b];
  const int m = bbase[b + 1] - rb;
  for (int j = t; j < m; j += 256) atomicAdd(&c_s[dump[rb + j] & 63], 1);
  __syncthreads();
  if (t < 64) {
    int n = (b << 6) + t;
    if (n < N_NODES) cnt[n] = c_s[t];
  }
}

// hs[n] = fp16( rsqrt(cnt[n]+1) * (x @ W1)[n] )  via MFMA f16
__global__ __launch_bounds__(256, 3) void k_gemm1(
    const float* __restrict__ x, const __half* __restrict__ Wt,
    const int* __restrict__ cnt, __half* __restrict__ hs) {
  __shared__ _Float16 xt[64 * 136];
  __shared__ _Float16 wt[128 * 136];
  const int t = threadIdx.x;
  const int row0 = blockIdx.x * 64;
#pragma unroll
  for (int i = 0; i < 8; ++i) {
    int lin = i * 256 + t;
    int r = lin >> 5, c4 = lin & 31;
    int gr = row0 + r;
    float4 v = make_float4(0.f, 0.f, 0.f, 0.f);
    if (gr < N_NODES) v = *(const float4*)(x + (size_t)gr * 128 + c4 * 4);
    union { __half2 h2[2]; int2 iv; } u;
    u.h2[0] = __floats2half2_rn(v.x, v.y);
    u.h2[1] = __floats2half2_rn(v.z, v.w);
    *(int2*)&xt[r * 136 + c4 * 4] = u.iv;
  }
#pragma unroll
  for (int i = 0; i < 8; ++i) {
    int lin = i * 256 + t;
    int n = lin >> 4, kb = lin & 15;
    int4 v = *(const int4*)(Wt + (size_t)n * 128 + kb * 8);
    *(int4*)&wt[n * 136 + kb * 8] = v;
  }
  __syncthreads();

  const int w = t >> 6, l = t & 63;
  const int r = l & 15, g = l >> 4;
  const _Float16* ap = &xt[(w * 16 + r) * 136 + g * 8];
  half8_t af[4];
#pragma unroll
  for (int ks = 0; ks < 4; ++ks) af[ks] = *(const half8_t*)&ap[ks * 32];

  const int rbase = row0 + w * 16 + g * 4;
  float dv[4];
#pragma unroll
  for (int j = 0; j < 4; ++j) {
    int rr = rbase + j;
    dv[j] = (rr < N_NODES) ? rsqrtf((float)cnt[rr] + 1.0f) : 0.f;
  }

#pragma unroll
  for (int ct = 0; ct < 8; ++ct) {
    f32x4_t acc = {0.f, 0.f, 0.f, 0.f};
    const _Float16* bp = &wt[(ct * 16 + r) * 136 + g * 8];
#pragma unroll
    for (int ks = 0; ks < 4; ++ks) {
      half8_t bf = *(const half8_t*)&bp[ks * 32];
      acc = __builtin_amdgcn_mfma_f32_16x16x32_f16(af[ks], bf, acc, 0, 0, 0);
    }
#pragma unroll
    for (int j = 0; j < 4; ++j) {
      int rr = rbase + j;
      if (rr < N_NODES)
        hs[(size_t)rr * 128 + ct * 16 + r] = __float2half(acc[j] * dv[j]);
    }
  }
}

// fully fused per bucket (64 nodes, 512 threads):
// CSR placement -> gather-aggregate (regs) -> relu'd fp16 rows in LDS ->
// Linear(linW,linb) -> log_softmax -> out.  No acc round-trip.
__global__ __launch_bounds__(512) void k_aggfin(
    const __half* __restrict__ hs, const int* __restrict__ dump,
    const int* __restrict__ bbase, const int* __restrict__ cnt,
    const float* __restrict__ b1, const float* __restrict__ linW,
    const float* __restrict__ linb, float* __restrict__ out) {
  __shared__ int stage[4352];          // 17408 B; aliased as vs[64][136] halves
  __shared__ float wl[128 * 40];
  __shared__ float lb[40];
  __shared__ int cnt_s[64];
  __shared__ int off_s[64];
  __shared__ int cur_s[64];
  _Float16* vs = (_Float16*)stage;

  const int t = threadIdx.x;
  const int b = blockIdx.x;
  const int n0 = b << 6;
  if (t < 64) {
    int n = n0 + t;
    int v = (n < N_NODES) ? cnt[n] : 0;
    cnt_s[t] = v;
    int sv = v;
    for (int d = 1; d < 64; d <<= 1) {
      int u = __shfl_up(sv, d);
      if (t >= d) sv += u;
    }
    off_s[t] = sv - v;
    cur_s[t] = sv - v;
  }
  // stage linW (f32) + linb while header runs
#pragma unroll
  for (int i = 0; i < 3; ++i) {
    int lin = i * 512 + t;
    if (lin < 1280) ((float4*)wl)[lin] = ((const float4*)linW)[lin];
  }
  if (t < 40) lb[t] = linb[t];
  __syncthreads();

  const int rb = bbase[b];
  const int m = bbase[b + 1] - rb;
  for (int j = t; j < m; j += 512) {
    int rec = dump[rb + j];
    int p = atomicAdd(&cur_s[rec & 63], 1);
    stage[p] = rec >> 6;
  }
  __syncthreads();

  // gather-aggregate: half-wave hw handles nodes hw, hw+16, hw+32, hw+48
  const int hw = t >> 5, lane = t & 31;
  uint2 res[4];
#pragma unroll
  for (int mi = 0; mi < 4; ++mi) {
    res[mi] = make_uint2(0u, 0u);
    const int i = hw + mi * 16;
    const int n = n0 + i;
    if (n >= N_NODES) continue;
    float4 sum;
    {
      uint2 raw = *(const uint2*)(hs + (size_t)n * 128 + lane * 4);  // self-loop
      float2 fa = __half22float2(*(__half2*)&raw.x);
      float2 fb = __half22float2(*(__half2*)&raw.y);
      sum = make_float4(fa.x, fa.y, fb.x, fb.y);
    }
    int j = off_s[i];
    const int e0 = off_s[i] + cnt_s[i];
    for (; j + 8 <= e0; j += 8) {
      uint2 r[8];
#pragma unroll
      for (int q = 0; q < 8; ++q) {
        int src = stage[j + q];
        r[q] = *(const uint2*)(hs + (size_t)src * 128 + lane * 4);
      }
#pragma unroll
      for (int q = 0; q < 8; ++q) {
        float2 a = __half22float2(*(__half2*)&r[q].x);
        float2 bf = __half22float2(*(__half2*)&r[q].y);
        sum.x += a.x; sum.y += a.y; sum.z += bf.x; sum.w += bf.y;
      }
    }
    if (j + 4 <= e0) {
      uint2 r[4];
#pragma unroll
      for (int q = 0; q < 4; ++q) {
        int src = stage[j + q];
        r[q] = *(const uint2*)(hs + (size_t)src * 128 + lane * 4);
      }
#pragma unroll
      for (int q = 0; q < 4; ++q) {
        float2 a = __half22float2(*(__half2*)&r[q].x);
        float2 bf = __half22float2(*(__half2*)&r[q].y);
        sum.x += a.x; sum.y += a.y; sum.z += bf.x; sum.w += bf.y;
      }
      j += 4;
    }
    for (; j < e0; ++j) {
      int src = stage[j];
      uint2 r0 = *(const uint2*)(hs + (size_t)src * 128 + lane * 4);
      float2 a0 = __half22float2(*(__half2*)&r0.x);
      float2 b0 = __half22float2(*(__half2*)&r0.y);
      sum.x += a0.x; sum.y += a0.y; sum.z += b0.x; sum.w += b0.y;
    }
    float d = rsqrtf((float)cnt_s[i] + 1.0f);
    float4 bb = *(const float4*)(b1 + lane * 4);
    // relu( fp16( d*sum + b1 ) ), kept as fp16 — matches old acc+k_final numerics
    union { __half2 h[2]; uint2 v; } u;
    u.h[0] = __floats2half2_rn(fmaxf(fmaf(d, sum.x, bb.x), 0.f),
                               fmaxf(fmaf(d, sum.y, bb.y), 0.f));
    u.h[1] = __floats2half2_rn(fmaxf(fmaf(d, sum.z, bb.z), 0.f),
                               fmaxf(fmaf(d, sum.w, bb.w), 0.f));
    res[mi] = u.v;
  }
  __syncthreads();  // stage (records) now dead -> reuse as vs
#pragma unroll
  for (int mi = 0; mi < 4; ++mi) {
    const int i = hw + mi * 16;
    *(uint2*)&vs[i * 136 + lane * 4] = res[mi];
  }
  __syncthreads();

  // final: node = t>>3 (64 nodes), 5 classes per 8-lane slot
  const int node = t >> 3;
  const int cg = (t & 7) * 5;
  const int n = n0 + node;
  float lg[5];
#pragma unroll
  for (int j = 0; j < 5; ++j) lg[j] = lb[cg + j];
#pragma unroll
  for (int kb = 0; kb < 16; ++kb) {
    half8_t hv = *(const half8_t*)&vs[node * 136 + kb * 8];
#pragma unroll
    for (int q = 0; q < 8; ++q) {
      float a = (float)hv[q];
      const float* wr = wl + (kb * 8 + q) * 40 + cg;
#pragma unroll
      for (int j = 0; j < 5; ++j) lg[j] = fmaf(a, wr[j], lg[j]);
    }
  }
  float mx = lg[0];
#pragma unroll
  for (int j = 1; j < 5; ++j) mx = fmaxf(mx, lg[j]);
  mx = fmaxf(mx, __shfl_xor(mx, 1));
  mx = fmaxf(mx, __shfl_xor(mx, 2));
  mx = fmaxf(mx, __shfl_xor(mx, 4));
  float ssum = 0.f;
#pragma unroll
  for (int j = 0; j < 5; ++j) ssum += expf(lg[j] - mx);
  ssum += __shfl_xor(ssum, 1);
  ssum += __shfl_xor(ssum, 2);
  ssum += __shfl_xor(ssum, 4);
  float lse = mx + logf(ssum);
  if (n < N_NODES) {
#pragma unroll
    for (int j = 0; j < 5; ++j) out[(size_t)n * 40 + cg + j] = lg[j] - lse;
  }
}

extern "C" void kernel_launch(void* const* d_in, const int* in_sizes, int n_in,
                              void* d_out, int out_size, void* d_ws, size_t ws_size,
                              hipStream_t stream) {
  const float* x    = (const float*)d_in[0];
  const int*   ei   = (const int*)d_in[1];
  const float* W1   = (const float*)d_in[2];
  const float* b1   = (const float*)d_in[3];
  const float* linW = (const float*)d_in[4];
  const float* linb = (const float*)d_in[5];
  float* out = (float*)d_out;
  char* ws = (char*)d_ws;

  int*    btot   = (int*)(ws + OFF_BTOT);
  int*    bbase  = (int*)(ws + OFF_BBASE);
  int*    cnt    = (int*)(ws + OFF_CNT);
  __half* hs     = (__half*)(ws + OFF_HS);
  __half* Wt     = (__half*)(ws + OFF_WT);
  int*    ghist  = (int*)(ws + OFF_GHIST);
  int*    gchoff = (int*)(ws + OFF_GCHOFF);
  int*    dump   = (int*)(ws + OFF_DUMP);

  k_hist<<<NB_HIST + 16, 256, 0, stream>>>(ei, ghist, W1, Wt);
  k_bucket_scan<<<NBUCK, 256, 0, stream>>>(ghist, gchoff, btot);
  k_scan_tot<<<1, 1024, 0, stream>>>(btot, bbase);
  k_bin<<<NB_BIN, 512, 0, stream>>>(ei, bbase, gchoff, dump);
  k_deg<<<NBUCK, 256, 0, stream>>>(dump, bbase, cnt);
  k_gemm1<<<NBUCK, 256, 0, stream>>>(x, Wt, cnt, hs);
  k_aggfin<<<NBUCK, 512, 0, stream>>>(hs, dump, bbase, cnt, b1, linW, linb, out);
}

// Round 12
// 132.917 us; speedup vs baseline: 1.6952x; 1.1416x over previous
//
#include <hip/hip_runtime.h>
#include <hip/hip_fp16.h>
#include <math.h>

#define N_NODES 100000
#define N_EDGES 1600000
#define NBUCK   1563          // ceil(100000/64) buckets of 64 dst nodes
#define NBUCK_P 1568          // padded row length for hist tables
#define NB_HIST 256           // hist blocks (slice 6250)
#define NB_BIN  256           // bin blocks (slice 6250, same rows as hist)

// ws layout (bytes)
#define OFF_BTOT   0x1000u     // int[NBUCK_P] bucket totals
#define OFF_BBASE  0x5000u     // int[NBUCK+1] scan of totals (dump base, exact)
#define OFF_CNT    0x70000u    // int[N_NODES] in-degree (written once by k_deg)
#define OFF_HS     0x780000u   // __half[N_NODES*128] (25.6 MB)
#define OFF_WT     0x2100000u  // __half[128*128] fp16 W1^T (32 KB)
#define OFF_WLT    0x2110000u  // __half[64*128]  fp16 linW^T, class-padded (16 KB)
#define OFF_GHIST  0x3980000u  // int[NB_HIST*NBUCK_P]  (1.6 MB)
#define OFF_GCHOFF 0x3B10000u  // int[NB_BIN*NBUCK_P]   (1.6 MB)
#define OFF_DUMP   0x3CA0000u  // int[N_EDGES] packed (6.4 MB, ends 0x42C0000)

typedef _Float16 half8_t __attribute__((ext_vector_type(8)));
typedef float f32x4_t __attribute__((ext_vector_type(4)));
typedef float f32x16_t __attribute__((ext_vector_type(16)));

// blocks [0,255]: per-block bucket histogram of dst (inline dtype detect).
// blocks [256,271]: W1 (f32 [128k][128n]) -> Wt fp16 [128n][128k].
// block  272:       linW (f32 [128k][40c]) -> WlT fp16 [64c][128k] (pad c>=40 = 0).
__global__ __launch_bounds__(256) void k_hist(const int* __restrict__ p32,
                                              int* __restrict__ G_hist,
                                              const float* __restrict__ W,
                                              __half* __restrict__ Wt,
                                              const float* __restrict__ linW,
                                              __half* __restrict__ WlT) {
  const int t = threadIdx.x;
  if (blockIdx.x == NB_HIST + 16) {  // ---- linW transpose ----
    __shared__ float buf[5120];
#pragma unroll
    for (int i = 0; i < 5; ++i) {
      int lin = i * 256 + t;  // 1280 float4s = 5120 floats
      ((float4*)buf)[lin] = ((const float4*)linW)[lin];
    }
    __syncthreads();
#pragma unroll
    for (int i = 0; i < 4; ++i) {
      int lin = i * 256 + t;  // 1024 int4s = 64 rows x 16
      int c = lin >> 4, kb = lin & 15;
      union { __half h[8]; int4 v; } u;
#pragma unroll
      for (int q = 0; q < 8; ++q)
        u.h[q] = (c < 40) ? __float2half(buf[(kb * 8 + q) * 40 + c])
                          : __float2half(0.f);
      *(int4*)&WlT[(size_t)c * 128 + kb * 8] = u.v;
    }
    return;
  }
  if (blockIdx.x >= NB_HIST) {  // ---- W1 transpose ----
    __shared__ float buf1[1024];
    const int b = blockIdx.x - NB_HIST;
    float4 v = ((const float4*)(W + (size_t)b * 1024))[t];
    *(float4*)&buf1[t * 4] = v;
    __syncthreads();
    if (t < 128) {
      union { __half h[8]; int4 v; } u;
#pragma unroll
      for (int k = 0; k < 8; ++k) u.h[k] = __float2half(buf1[k * 128 + t]);
      *(int4*)&Wt[(size_t)t * 128 + b * 8] = u.v;
    }
    return;
  }
  __shared__ int hist[NBUCK];
  __shared__ int nz;
  if (t == 0) nz = 0;
  for (int i = t; i < NBUCK; i += 256) hist[i] = 0;
  __syncthreads();
  if (p32[2 * t + 1] != 0) atomicAdd(&nz, 1);
  __syncthreads();
  const int s = (nz == 0) ? 1 : 0;  // 1 => int64 (stride 2)
  const int base = blockIdx.x * 6250;
  for (int i = 0; i < 25; ++i) {
    int e = base + i * 256 + t;
    if (e < base + 6250) {
      int c = p32[((size_t)(N_EDGES + e)) << s];
      atomicAdd(&hist[c >> 6], 1);
    }
  }
  __syncthreads();
  for (int i = t; i < NBUCK; i += 256) G_hist[blockIdx.x * NBUCK_P + i] = hist[i];
}

// per bucket: scan 256 exact chunk sizes -> per-binblock offsets + total
__global__ __launch_bounds__(256) void k_bucket_scan(const int* __restrict__ G_hist,
                                                     int* __restrict__ G_choff,
                                                     int* __restrict__ btot) {
  __shared__ int wsum[4];
  const int t = threadIdx.x;
  const int b = blockIdx.x;
  const int c = G_hist[t * NBUCK_P + b];
  int sv = c;
  const int lane = t & 63;
  for (int d = 1; d < 64; d <<= 1) {
    int a = __shfl_up(sv, d);
    if (lane >= d) sv += a;
  }
  if (lane == 63) wsum[t >> 6] = sv;
  __syncthreads();
  int o = 0;
  for (int w2 = 0; w2 < (t >> 6); ++w2) o += wsum[w2];
  G_choff[t * NBUCK_P + b] = o + sv - c;  // exclusive offset within bucket
  if (t == 255) btot[b] = o + sv;
}

// scan 1563 totals -> bbase[0..NBUCK] (exclusive), 1 block
__global__ __launch_bounds__(1024) void k_scan_tot(const int* __restrict__ tot,
                                                   int* __restrict__ base) {
  __shared__ int sm[1024];
  const int t = threadIdx.x;
  int a = (2 * t < NBUCK) ? tot[2 * t] : 0;
  int bb = (2 * t + 1 < NBUCK) ? tot[2 * t + 1] : 0;
  int pair = a + bb;
  sm[t] = pair;
  __syncthreads();
  for (int off = 1; off < 1024; off <<= 1) {
    int x = (t >= off) ? sm[t - off] : 0;
    __syncthreads();
    sm[t] += x;
    __syncthreads();
  }
  int S = sm[t];
  if (2 * t <= NBUCK) base[2 * t] = S - pair;
  if (2 * t + 1 <= NBUCK) base[2 * t + 1] = S - bb;
}

// place packed (src<<6|ldst) records into block-private chunks (no global atomics)
__global__ __launch_bounds__(512) void k_bin(const int* __restrict__ p32,
                                             const int* __restrict__ bbase,
                                             const int* __restrict__ G_choff,
                                             int* __restrict__ dump) {
  __shared__ int gb[NBUCK];
  __shared__ int cur[NBUCK];
  __shared__ int nz;
  const int t = threadIdx.x;
  const int blk = blockIdx.x;
  if (t == 0) nz = 0;
  for (int i = t; i < NBUCK; i += 512) {
    gb[i] = bbase[i] + G_choff[blk * NBUCK_P + i];
    cur[i] = 0;
  }
  __syncthreads();
  if (t < 256 && p32[2 * t + 1] != 0) atomicAdd(&nz, 1);
  __syncthreads();
  const int s = (nz == 0) ? 1 : 0;
  const int base = blk * 6250;
  for (int i = 0; i < 13; ++i) {
    int e = base + i * 512 + t;
    if (e < base + 6250) {
      int r = p32[((size_t)e) << s];
      int c = p32[((size_t)(N_EDGES + e)) << s];
      int bk = c >> 6;
      int p = atomicAdd(&cur[bk], 1);
      dump[gb[bk] + p] = (r << 6) | (c & 63);
    }
  }
}

// per bucket: degree from dump chunk (LDS counts, one coalesced write)
__global__ __launch_bounds__(256) void k_deg(const int* __restrict__ dump,
                                             const int* __restrict__ bbase,
                                             int* __restrict__ cnt) {
  __shared__ int c_s[64];
  const int t = threadIdx.x;
  const int b = blockIdx.x;
  if (t < 64) c_s[t] = 0;
  __syncthreads();
  const int rb = bbase[b];
  const int m = bbase[b + 1] - rb;
  for (int j = t; j < m; j += 256) atomicAdd(&c_s[dump[rb + j] & 63], 1);
  __syncthreads();
  if (t < 64) {
    int n = (b << 6) + t;
    if (n < N_NODES) cnt[n] = c_s[t];
  }
}

// hs[n] = fp16( rsqrt(cnt[n]+1) * (x @ W1)[n] )  via MFMA f16
__global__ __launch_bounds__(256, 3) void k_gemm1(
    const float* __restrict__ x, const __half* __restrict__ Wt,
    const int* __restrict__ cnt, __half* __restrict__ hs) {
  __shared__ _Float16 xt[64 * 136];
  __shared__ _Float16 wt[128 * 136];
  const int t = threadIdx.x;
  const int row0 = blockIdx.x * 64;
#pragma unroll
  for (int i = 0; i < 8; ++i) {
    int lin = i * 256 + t;
    int r = lin >> 5, c4 = lin & 31;
    int gr = row0 + r;
    float4 v = make_float4(0.f, 0.f, 0.f, 0.f);
    if (gr < N_NODES) v = *(const float4*)(x + (size_t)gr * 128 + c4 * 4);
    union { __half2 h2[2]; int2 iv; } u;
    u.h2[0] = __floats2half2_rn(v.x, v.y);
    u.h2[1] = __floats2half2_rn(v.z, v.w);
    *(int2*)&xt[r * 136 + c4 * 4] = u.iv;
  }
#pragma unroll
  for (int i = 0; i < 8; ++i) {
    int lin = i * 256 + t;
    int n = lin >> 4, kb = lin & 15;
    int4 v = *(const int4*)(Wt + (size_t)n * 128 + kb * 8);
    *(int4*)&wt[n * 136 + kb * 8] = v;
  }
  __syncthreads();

  const int w = t >> 6, l = t & 63;
  const int r = l & 15, g = l >> 4;
  const _Float16* ap = &xt[(w * 16 + r) * 136 + g * 8];
  half8_t af[4];
#pragma unroll
  for (int ks = 0; ks < 4; ++ks) af[ks] = *(const half8_t*)&ap[ks * 32];

  const int rbase = row0 + w * 16 + g * 4;
  float dv[4];
#pragma unroll
  for (int j = 0; j < 4; ++j) {
    int rr = rbase + j;
    dv[j] = (rr < N_NODES) ? rsqrtf((float)cnt[rr] + 1.0f) : 0.f;
  }

#pragma unroll
  for (int ct = 0; ct < 8; ++ct) {
    f32x4_t acc = {0.f, 0.f, 0.f, 0.f};
    const _Float16* bp = &wt[(ct * 16 + r) * 136 + g * 8];
#pragma unroll
    for (int ks = 0; ks < 4; ++ks) {
      half8_t bf = *(const half8_t*)&bp[ks * 32];
      acc = __builtin_amdgcn_mfma_f32_16x16x32_f16(af[ks], bf, acc, 0, 0, 0);
    }
#pragma unroll
    for (int j = 0; j < 4; ++j) {
      int rr = rbase + j;
      if (rr < N_NODES)
        hs[(size_t)rr * 128 + ct * 16 + r] = __float2half(acc[j] * dv[j]);
    }
  }
}

// fully fused per bucket (64 nodes, 512 threads):
// CSR placement -> gather-aggregate (regs) -> relu'd fp16 rows in LDS ->
// MFMA Linear (fp16 WlT) -> log_softmax -> out.
__global__ __launch_bounds__(512, 8) void k_aggfin(
    const __half* __restrict__ hs, const int* __restrict__ dump,
    const int* __restrict__ bbase, const int* __restrict__ cnt,
    const float* __restrict__ b1, const __half* __restrict__ WlT,
    const float* __restrict__ linb, float* __restrict__ out) {
  __shared__ int stage[4352];          // 17408 B; alias vs[64][136] f16, outbuf[64][68] f32
  __shared__ _Float16 wlt[64 * 136];   // 17408 B
  __shared__ float lb_s[64];
  __shared__ int cnt_s[64];
  __shared__ int off_s[64];
  __shared__ int cur_s[64];
  _Float16* vs = (_Float16*)stage;
  float* outbuf = (float*)stage;

  const int t = threadIdx.x;
  const int b = blockIdx.x;
  const int n0 = b << 6;
  if (t < 64) {
    int n = n0 + t;
    int v = (n < N_NODES) ? cnt[n] : 0;
    cnt_s[t] = v;
    int sv = v;
    for (int d = 1; d < 64; d <<= 1) {
      int u = __shfl_up(sv, d);
      if (t >= d) sv += u;
    }
    off_s[t] = sv - v;
    cur_s[t] = sv - v;
  }
  // stage WlT (fp16, class-padded) and bias
#pragma unroll
  for (int i = 0; i < 2; ++i) {
    int lin = i * 512 + t;  // 1024 int4s = 64 rows x 16
    int c = lin >> 4, kb = lin & 15;
    int4 v = *(const int4*)(WlT + (size_t)c * 128 + kb * 8);
    *(int4*)&wlt[c * 136 + kb * 8] = v;
  }
  if (t < 64) lb_s[t] = (t < 40) ? linb[t] : 0.f;
  __syncthreads();

  const int rb = bbase[b];
  const int m = bbase[b + 1] - rb;
  for (int j = t; j < m; j += 512) {
    int rec = dump[rb + j];
    int p = atomicAdd(&cur_s[rec & 63], 1);
    stage[p] = rec >> 6;
  }
  __syncthreads();

  // gather-aggregate: half-wave hw handles nodes hw, hw+16, hw+32, hw+48
  const int hw = t >> 5, lane = t & 31;
  uint2 res[4];
#pragma unroll
  for (int mi = 0; mi < 4; ++mi) {
    res[mi] = make_uint2(0u, 0u);
    const int i = hw + mi * 16;
    const int n = n0 + i;
    if (n >= N_NODES) continue;
    float4 sum;
    {
      uint2 raw = *(const uint2*)(hs + (size_t)n * 128 + lane * 4);  // self-loop
      float2 fa = __half22float2(*(__half2*)&raw.x);
      float2 fb = __half22float2(*(__half2*)&raw.y);
      sum = make_float4(fa.x, fa.y, fb.x, fb.y);
    }
    int j = off_s[i];
    const int e0 = off_s[i] + cnt_s[i];
    for (; j + 8 <= e0; j += 8) {
      uint2 r[8];
#pragma unroll
      for (int q = 0; q < 8; ++q) {
        int src = stage[j + q];
        r[q] = *(const uint2*)(hs + (size_t)src * 128 + lane * 4);
      }
#pragma unroll
      for (int q = 0; q < 8; ++q) {
        float2 a = __half22float2(*(__half2*)&r[q].x);
        float2 bf = __half22float2(*(__half2*)&r[q].y);
        sum.x += a.x; sum.y += a.y; sum.z += bf.x; sum.w += bf.y;
      }
    }
    if (j + 4 <= e0) {
      uint2 r[4];
#pragma unroll
      for (int q = 0; q < 4; ++q) {
        int src = stage[j + q];
        r[q] = *(const uint2*)(hs + (size_t)src * 128 + lane * 4);
      }
#pragma unroll
      for (int q = 0; q < 4; ++q) {
        float2 a = __half22float2(*(__half2*)&r[q].x);
        float2 bf = __half22float2(*(__half2*)&r[q].y);
        sum.x += a.x; sum.y += a.y; sum.z += bf.x; sum.w += bf.y;
      }
      j += 4;
    }
    for (; j < e0; ++j) {
      int src = stage[j];
      uint2 r0 = *(const uint2*)(hs + (size_t)src * 128 + lane * 4);
      float2 a0 = __half22float2(*(__half2*)&r0.x);
      float2 b0 = __half22float2(*(__half2*)&r0.y);
      sum.x += a0.x; sum.y += a0.y; sum.z += b0.x; sum.w += b0.y;
    }
    float d = rsqrtf((float)cnt_s[i] + 1.0f);
    float4 bb = *(const float4*)(b1 + lane * 4);
    union { __half2 h[2]; uint2 v; } u;
    u.h[0] = __floats2half2_rn(fmaxf(fmaf(d, sum.x, bb.x), 0.f),
                               fmaxf(fmaf(d, sum.y, bb.y), 0.f));
    u.h[1] = __floats2half2_rn(fmaxf(fmaf(d, sum.z, bb.z), 0.f),
                               fmaxf(fmaf(d, sum.w, bb.w), 0.f));
    res[mi] = u.v;
  }
  __syncthreads();  // stage (records) dead -> reuse as vs
#pragma unroll
  for (int mi = 0; mi < 4; ++mi) {
    const int i = hw + mi * 16;
    *(uint2*)&vs[i * 136 + lane * 4] = res[mi];
  }
  __syncthreads();

  // MFMA Linear: vs[64x128] @ wlt^T -> logits 64x64 (cols>=40 ignored).
  // 2x2 tiles of 32x32 on waves 0..3; mirrors k_gemm1 fragment addressing.
  const int wv = t >> 6, l64 = t & 63;
  f32x16_t C = {};
  int colg = 0, lbv_valid = 0;
  float lbv = 0.f;
  if (wv < 4) {
    const int rowt = wv >> 1, colt = wv & 1;
    const int rw = l64 & 31, kg = l64 >> 5;  // kg in {0,1}
    const _Float16* ap = &vs[(rowt * 32 + rw) * 136 + kg * 8];
    const _Float16* bp = &wlt[(colt * 32 + rw) * 136 + kg * 8];
#pragma unroll
    for (int ks = 0; ks < 8; ++ks) {
      half8_t af = *(const half8_t*)&ap[ks * 16];
      half8_t bf = *(const half8_t*)&bp[ks * 16];
      C = __builtin_amdgcn_mfma_f32_32x32x16_f16(af, bf, C, 0, 0, 0);
    }
    colg = colt * 32 + rw;
    lbv = lb_s[colg];
    lbv_valid = 1;
  }
  __syncthreads();  // all vs reads done -> safe to overwrite as outbuf
  if (lbv_valid && colg < 40) {
    const int rowt = (t >> 6) >> 1;
    const int hi = (t & 63) >> 5;
#pragma unroll
    for (int q = 0; q < 16; ++q) {
      int row = (q & 3) + 8 * (q >> 2) + 4 * hi;  // C/D layout (m74/m101)
      outbuf[(rowt * 32 + row) * 68 + colg] = C[q] + lbv;
    }
  }
  __syncthreads();

  // softmax: node = t>>3, 5 classes per lane
  const int node = t >> 3;
  const int cg = (t & 7) * 5;
  const int n = n0 + node;
  float lg[5];
#pragma unroll
  for (int j = 0; j < 5; ++j) lg[j] = outbuf[node * 68 + cg + j];
  float mx = lg[0];
#pragma unroll
  for (int j = 1; j < 5; ++j) mx = fmaxf(mx, lg[j]);
  mx = fmaxf(mx, __shfl_xor(mx, 1));
  mx = fmaxf(mx, __shfl_xor(mx, 2));
  mx = fmaxf(mx, __shfl_xor(mx, 4));
  float ssum = 0.f;
#pragma unroll
  for (int j = 0; j < 5; ++j) ssum += expf(lg[j] - mx);
  ssum += __shfl_xor(ssum, 1);
  ssum += __shfl_xor(ssum, 2);
  ssum += __shfl_xor(ssum, 4);
  float lse = mx + logf(ssum);
  if (n < N_NODES) {
#pragma unroll
    for (int j = 0; j < 5; ++j) out[(size_t)n * 40 + cg + j] = lg[j] - lse;
  }
}

extern "C" void kernel_launch(void* const* d_in, const int* in_sizes, int n_in,
                              void* d_out, int out_size, void* d_ws, size_t ws_size,
                              hipStream_t stream) {
  const float* x    = (const float*)d_in[0];
  const int*   ei   = (const int*)d_in[1];
  const float* W1   = (const float*)d_in[2];
  const float* b1   = (const float*)d_in[3];
  const float* linW = (const float*)d_in[4];
  const float* linb = (const float*)d_in[5];
  float* out = (float*)d_out;
  char* ws = (char*)d_ws;

  int*    btot   = (int*)(ws + OFF_BTOT);
  int*    bbase  = (int*)(ws + OFF_BBASE);
  int*    cnt    = (int*)(ws + OFF_CNT);
  __half* hs     = (__half*)(ws + OFF_HS);
  __half* Wt     = (__half*)(ws + OFF_WT);
  __half* WlT    = (__half*)(ws + OFF_WLT);
  int*    ghist  = (int*)(ws + OFF_GHIST);
  int*    gchoff = (int*)(ws + OFF_GCHOFF);
  int*    dump   = (int*)(ws + OFF_DUMP);

  k_hist<<<NB_HIST + 17, 256, 0, stream>>>(ei, ghist, W1, Wt, linW, WlT);
  k_bucket_scan<<<NBUCK, 256, 0, stream>>>(ghist, gchoff, btot);
  k_scan_tot<<<1, 1024, 0, stream>>>(btot, bbase);
  k_bin<<<NB_BIN, 512, 0, stream>>>(ei, bbase, gchoff, dump);
  k_deg<<<NBUCK, 256, 0, stream>>>(dump, bbase, cnt);
  k_gemm1<<<NBUCK, 256, 0, stream>>>(x, Wt, cnt, hs);
  k_aggfin<<<NBUCK, 512, 0, stream>>>(hs, dump, bbase, cnt, b1, WlT, linb, out);
}

// Round 13
// 131.523 us; speedup vs baseline: 1.7131x; 1.0106x over previous
//
#include <hip/hip_runtime.h>
#include <hip/hip_fp16.h>
#include <math.h>

#define N_NODES 100000
#define N_EDGES 1600000
#define NBUCK   1563          // ceil(100000/64) buckets of 64 dst nodes
#define NBUCK_P 1568          // padded row length for hist tables
#define NB_HIST 256           // hist blocks (slice 6250)
#define NB_BIN  256           // bin blocks (slice 6250, same rows as hist)

// ws layout (bytes)
#define OFF_BTOT   0x1000u     // int[NBUCK_P] bucket totals
#define OFF_BBASE  0x5000u     // int[NBUCK+1] scan of totals (dump base, exact)
#define OFF_HS     0x780000u   // __half[N_NODES*128] (25.6 MB)
#define OFF_WT     0x2100000u  // __half[128*128] fp16 W1^T (32 KB)
#define OFF_WLT    0x2110000u  // __half[64*128]  fp16 linW^T, class-padded (16 KB)
#define OFF_GHIST  0x3980000u  // int[NB_HIST*NBUCK_P]  (1.6 MB)
#define OFF_GCHOFF 0x3B10000u  // int[NB_BIN*NBUCK_P]   (1.6 MB)
#define OFF_DUMP   0x3CA0000u  // int[N_EDGES] packed (6.4 MB, ends 0x42C0000)

typedef _Float16 half8_t __attribute__((ext_vector_type(8)));
typedef float f32x4_t __attribute__((ext_vector_type(4)));
typedef float f32x16_t __attribute__((ext_vector_type(16)));

// blocks [0,255]: per-block bucket histogram of dst (inline dtype detect).
// blocks [256,271]: W1 (f32 [128k][128n]) -> Wt fp16 [128n][128k].
// block  272:       linW (f32 [128k][40c]) -> WlT fp16 [64c][128k] (pad c>=40 = 0).
__global__ __launch_bounds__(256) void k_hist(const int* __restrict__ p32,
                                              int* __restrict__ G_hist,
                                              const float* __restrict__ W,
                                              __half* __restrict__ Wt,
                                              const float* __restrict__ linW,
                                              __half* __restrict__ WlT) {
  const int t = threadIdx.x;
  if (blockIdx.x == NB_HIST + 16) {  // ---- linW transpose ----
    __shared__ float buf[5120];
#pragma unroll
    for (int i = 0; i < 5; ++i) {
      int lin = i * 256 + t;  // 1280 float4s = 5120 floats
      ((float4*)buf)[lin] = ((const float4*)linW)[lin];
    }
    __syncthreads();
#pragma unroll
    for (int i = 0; i < 4; ++i) {
      int lin = i * 256 + t;  // 1024 int4s = 64 rows x 16
      int c = lin >> 4, kb = lin & 15;
      union { __half h[8]; int4 v; } u;
#pragma unroll
      for (int q = 0; q < 8; ++q)
        u.h[q] = (c < 40) ? __float2half(buf[(kb * 8 + q) * 40 + c])
                          : __float2half(0.f);
      *(int4*)&WlT[(size_t)c * 128 + kb * 8] = u.v;
    }
    return;
  }
  if (blockIdx.x >= NB_HIST) {  // ---- W1 transpose ----
    __shared__ float buf1[1024];
    const int b = blockIdx.x - NB_HIST;
    float4 v = ((const float4*)(W + (size_t)b * 1024))[t];
    *(float4*)&buf1[t * 4] = v;
    __syncthreads();
    if (t < 128) {
      union { __half h[8]; int4 v; } u;
#pragma unroll
      for (int k = 0; k < 8; ++k) u.h[k] = __float2half(buf1[k * 128 + t]);
      *(int4*)&Wt[(size_t)t * 128 + b * 8] = u.v;
    }
    return;
  }
  __shared__ int hist[NBUCK];
  __shared__ int nz;
  if (t == 0) nz = 0;
  for (int i = t; i < NBUCK; i += 256) hist[i] = 0;
  __syncthreads();
  if (p32[2 * t + 1] != 0) atomicAdd(&nz, 1);
  __syncthreads();
  const int s = (nz == 0) ? 1 : 0;  // 1 => int64 (stride 2)
  const int base = blockIdx.x * 6250;
  for (int i = 0; i < 25; ++i) {
    int e = base + i * 256 + t;
    if (e < base + 6250) {
      int c = p32[((size_t)(N_EDGES + e)) << s];
      atomicAdd(&hist[c >> 6], 1);
    }
  }
  __syncthreads();
  for (int i = t; i < NBUCK; i += 256) G_hist[blockIdx.x * NBUCK_P + i] = hist[i];
}

// per bucket: scan 256 exact chunk sizes -> per-binblock offsets + total
__global__ __launch_bounds__(256) void k_bucket_scan(const int* __restrict__ G_hist,
                                                     int* __restrict__ G_choff,
                                                     int* __restrict__ btot) {
  __shared__ int wsum[4];
  const int t = threadIdx.x;
  const int b = blockIdx.x;
  const int c = G_hist[t * NBUCK_P + b];
  int sv = c;
  const int lane = t & 63;
  for (int d = 1; d < 64; d <<= 1) {
    int a = __shfl_up(sv, d);
    if (lane >= d) sv += a;
  }
  if (lane == 63) wsum[t >> 6] = sv;
  __syncthreads();
  int o = 0;
  for (int w2 = 0; w2 < (t >> 6); ++w2) o += wsum[w2];
  G_choff[t * NBUCK_P + b] = o + sv - c;  // exclusive offset within bucket
  if (t == 255) btot[b] = o + sv;
}

// scan 1563 totals -> bbase[0..NBUCK] (exclusive), 1 block
__global__ __launch_bounds__(1024) void k_scan_tot(const int* __restrict__ tot,
                                                   int* __restrict__ base) {
  __shared__ int sm[1024];
  const int t = threadIdx.x;
  int a = (2 * t < NBUCK) ? tot[2 * t] : 0;
  int bb = (2 * t + 1 < NBUCK) ? tot[2 * t + 1] : 0;
  int pair = a + bb;
  sm[t] = pair;
  __syncthreads();
  for (int off = 1; off < 1024; off <<= 1) {
    int x = (t >= off) ? sm[t - off] : 0;
    __syncthreads();
    sm[t] += x;
    __syncthreads();
  }
  int S = sm[t];
  if (2 * t <= NBUCK) base[2 * t] = S - pair;
  if (2 * t + 1 <= NBUCK) base[2 * t + 1] = S - bb;
}

// place packed (src<<6|ldst) records into block-private chunks (no global atomics)
__global__ __launch_bounds__(512) void k_bin(const int* __restrict__ p32,
                                             const int* __restrict__ bbase,
                                             const int* __restrict__ G_choff,
                                             int* __restrict__ dump) {
  __shared__ int gb[NBUCK];
  __shared__ int cur[NBUCK];
  __shared__ int nz;
  const int t = threadIdx.x;
  const int blk = blockIdx.x;
  if (t == 0) nz = 0;
  for (int i = t; i < NBUCK; i += 512) {
    gb[i] = bbase[i] + G_choff[blk * NBUCK_P + i];
    cur[i] = 0;
  }
  __syncthreads();
  if (t < 256 && p32[2 * t + 1] != 0) atomicAdd(&nz, 1);
  __syncthreads();
  const int s = (nz == 0) ? 1 : 0;
  const int base = blk * 6250;
  for (int i = 0; i < 13; ++i) {
    int e = base + i * 512 + t;
    if (e < base + 6250) {
      int r = p32[((size_t)e) << s];
      int c = p32[((size_t)(N_EDGES + e)) << s];
      int bk = c >> 6;
      int p = atomicAdd(&cur[bk], 1);
      dump[gb[bk] + p] = (r << 6) | (c & 63);
    }
  }
}

// hs[n] = fp16( rsqrt(deg[n]+1) * (x @ W1)[n] )  via MFMA f16.
// deg computed in-block from this bucket's dump chunk (block b == bucket b).
__global__ __launch_bounds__(256, 3) void k_gemm1(
    const float* __restrict__ x, const __half* __restrict__ Wt,
    const int* __restrict__ dump, const int* __restrict__ bbase,
    __half* __restrict__ hs) {
  __shared__ _Float16 xt[64 * 136];
  __shared__ _Float16 wt[128 * 136];
  __shared__ int c_s[64];
  const int t = threadIdx.x;
  const int b = blockIdx.x;
  const int row0 = b * 64;
  if (t < 64) c_s[t] = 0;
  __syncthreads();
  // stage x tile -> fp16, Wt -> LDS, and count degrees (all overlap)
#pragma unroll
  for (int i = 0; i < 8; ++i) {
    int lin = i * 256 + t;
    int r = lin >> 5, c4 = lin & 31;
    int gr = row0 + r;
    float4 v = make_float4(0.f, 0.f, 0.f, 0.f);
    if (gr < N_NODES) v = *(const float4*)(x + (size_t)gr * 128 + c4 * 4);
    union { __half2 h2[2]; int2 iv; } u;
    u.h2[0] = __floats2half2_rn(v.x, v.y);
    u.h2[1] = __floats2half2_rn(v.z, v.w);
    *(int2*)&xt[r * 136 + c4 * 4] = u.iv;
  }
#pragma unroll
  for (int i = 0; i < 8; ++i) {
    int lin = i * 256 + t;
    int n = lin >> 4, kb = lin & 15;
    int4 v = *(const int4*)(Wt + (size_t)n * 128 + kb * 8);
    *(int4*)&wt[n * 136 + kb * 8] = v;
  }
  {
    const int rb = bbase[b];
    const int m = bbase[b + 1] - rb;
    for (int j = t; j < m; j += 256) atomicAdd(&c_s[dump[rb + j] & 63], 1);
  }
  __syncthreads();

  const int w = t >> 6, l = t & 63;
  const int r = l & 15, g = l >> 4;
  const _Float16* ap = &xt[(w * 16 + r) * 136 + g * 8];
  half8_t af[4];
#pragma unroll
  for (int ks = 0; ks < 4; ++ks) af[ks] = *(const half8_t*)&ap[ks * 32];

  const int lbase = w * 16 + g * 4;
  const int rbase = row0 + lbase;
  float dv[4];
#pragma unroll
  for (int j = 0; j < 4; ++j)
    dv[j] = rsqrtf((float)c_s[lbase + j] + 1.0f);

#pragma unroll
  for (int ct = 0; ct < 8; ++ct) {
    f32x4_t acc = {0.f, 0.f, 0.f, 0.f};
    const _Float16* bp = &wt[(ct * 16 + r) * 136 + g * 8];
#pragma unroll
    for (int ks = 0; ks < 4; ++ks) {
      half8_t bf = *(const half8_t*)&bp[ks * 32];
      acc = __builtin_amdgcn_mfma_f32_16x16x32_f16(af[ks], bf, acc, 0, 0, 0);
    }
#pragma unroll
    for (int j = 0; j < 4; ++j) {
      int rr = rbase + j;
      if (rr < N_NODES)
        hs[(size_t)rr * 128 + ct * 16 + r] = __float2half(acc[j] * dv[j]);
    }
  }
}

// fully fused per bucket (64 nodes, 512 threads):
// local deg + CSR placement (from dump, 2 passes) -> gather-aggregate
// (pk_f16 batches, f32 flush) -> relu'd fp16 rows in LDS ->
// MFMA Linear (fp16 WlT) -> log_softmax -> out.
__global__ __launch_bounds__(512, 8) void k_aggfin(
    const __half* __restrict__ hs, const int* __restrict__ dump,
    const int* __restrict__ bbase, const float* __restrict__ b1,
    const __half* __restrict__ WlT, const float* __restrict__ linb,
    float* __restrict__ out) {
  __shared__ int stage[4352];          // 17408 B; alias vs[64][136] f16, outbuf[64][68] f32
  __shared__ _Float16 wlt[64 * 136];   // 17408 B
  __shared__ float lb_s[64];
  __shared__ int cnt_s[64];
  __shared__ int off_s[64];
  __shared__ int cur_s[64];
  _Float16* vs = (_Float16*)stage;
  float* outbuf = (float*)stage;

  const int t = threadIdx.x;
  const int b = blockIdx.x;
  const int n0 = b << 6;
  if (t < 64) cnt_s[t] = 0;
  // stage WlT (fp16, class-padded) and bias
#pragma unroll
  for (int i = 0; i < 2; ++i) {
    int lin = i * 512 + t;  // 1024 int4s = 64 rows x 16
    int c = lin >> 4, kb = lin & 15;
    int4 v = *(const int4*)(WlT + (size_t)c * 128 + kb * 8);
    *(int4*)&wlt[c * 136 + kb * 8] = v;
  }
  if (t < 64) lb_s[t] = (t < 40) ? linb[t] : 0.f;
  __syncthreads();

  const int rb = bbase[b];
  const int m = bbase[b + 1] - rb;
  // pass 1: degree count
  for (int j = t; j < m; j += 512) atomicAdd(&cnt_s[dump[rb + j] & 63], 1);
  __syncthreads();
  if (t < 64) {
    int v = cnt_s[t];
    int sv = v;
    for (int d = 1; d < 64; d <<= 1) {
      int u = __shfl_up(sv, d);
      if (t >= d) sv += u;
    }
    off_s[t] = sv - v;
    cur_s[t] = sv - v;
  }
  __syncthreads();
  // pass 2: place src indices grouped by dst
  for (int j = t; j < m; j += 512) {
    int rec = dump[rb + j];
    int p = atomicAdd(&cur_s[rec & 63], 1);
    stage[p] = rec >> 6;
  }
  __syncthreads();

  // gather-aggregate: half-wave hw handles nodes hw, hw+16, hw+32, hw+48
  const int hw = t >> 5, lane = t & 31;
  uint2 res[4];
#pragma unroll
  for (int mi = 0; mi < 4; ++mi) {
    res[mi] = make_uint2(0u, 0u);
    const int i = hw + mi * 16;
    const int n = n0 + i;
    if (n >= N_NODES) continue;
    float4 sum;
    {
      uint2 raw = *(const uint2*)(hs + (size_t)n * 128 + lane * 4);  // self-loop
      float2 fa = __half22float2(*(__half2*)&raw.x);
      float2 fb = __half22float2(*(__half2*)&raw.y);
      sum = make_float4(fa.x, fa.y, fb.x, fb.y);
    }
    int j = off_s[i];
    const int e0 = off_s[i] + cnt_s[i];
    for (; j + 8 <= e0; j += 8) {
      uint2 r[8];
#pragma unroll
      for (int q = 0; q < 8; ++q) {
        int src = stage[j + q];
        r[q] = *(const uint2*)(hs + (size_t)src * 128 + lane * 4);
      }
      __half2 s01 = __float2half2_rn(0.f), s23 = __float2half2_rn(0.f);
#pragma unroll
      for (int q = 0; q < 8; ++q) {
        s01 = __hadd2(s01, *(const __half2*)&r[q].x);
        s23 = __hadd2(s23, *(const __half2*)&r[q].y);
      }
      float2 f01 = __half22float2(s01), f23 = __half22float2(s23);
      sum.x += f01.x; sum.y += f01.y; sum.z += f23.x; sum.w += f23.y;
    }
    if (j + 4 <= e0) {
      uint2 r[4];
#pragma unroll
      for (int q = 0; q < 4; ++q) {
        int src = stage[j + q];
        r[q] = *(const uint2*)(hs + (size_t)src * 128 + lane * 4);
      }
      __half2 s01 = __float2half2_rn(0.f), s23 = __float2half2_rn(0.f);
#pragma unroll
      for (int q = 0; q < 4; ++q) {
        s01 = __hadd2(s01, *(const __half2*)&r[q].x);
        s23 = __hadd2(s23, *(const __half2*)&r[q].y);
      }
      float2 f01 = __half22float2(s01), f23 = __half22float2(s23);
      sum.x += f01.x; sum.y += f01.y; sum.z += f23.x; sum.w += f23.y;
      j += 4;
    }
    for (; j < e0; ++j) {
      int src = stage[j];
      uint2 r0 = *(const uint2*)(hs + (size_t)src * 128 + lane * 4);
      float2 a0 = __half22float2(*(__half2*)&r0.x);
      float2 b0 = __half22float2(*(__half2*)&r0.y);
      sum.x += a0.x; sum.y += a0.y; sum.z += b0.x; sum.w += b0.y;
    }
    float d = rsqrtf((float)cnt_s[i] + 1.0f);
    float4 bb = *(const float4*)(b1 + lane * 4);
    union { __half2 h[2]; uint2 v; } u;
    u.h[0] = __floats2half2_rn(fmaxf(fmaf(d, sum.x, bb.x), 0.f),
                               fmaxf(fmaf(d, sum.y, bb.y), 0.f));
    u.h[1] = __floats2half2_rn(fmaxf(fmaf(d, sum.z, bb.z), 0.f),
                               fmaxf(fmaf(d, sum.w, bb.w), 0.f));
    res[mi] = u.v;
  }
  __syncthreads();  // stage (records) dead -> reuse as vs
#pragma unroll
  for (int mi = 0; mi < 4; ++mi) {
    const int i = hw + mi * 16;
    *(uint2*)&vs[i * 136 + lane * 4] = res[mi];
  }
  __syncthreads();

  // MFMA Linear: vs[64x128] @ wlt^T -> logits 64x64 (cols>=40 ignored).
  const int wv = t >> 6, l64 = t & 63;
  f32x16_t C = {};
  int colg = 0, lbv_valid = 0;
  float lbv = 0.f;
  if (wv < 4) {
    const int rowt = wv >> 1, colt = wv & 1;
    const int rw = l64 & 31, kg = l64 >> 5;  // kg in {0,1}
    const _Float16* ap = &vs[(rowt * 32 + rw) * 136 + kg * 8];
    const _Float16* bp = &wlt[(colt * 32 + rw) * 136 + kg * 8];
#pragma unroll
    for (int ks = 0; ks < 8; ++ks) {
      half8_t af = *(const half8_t*)&ap[ks * 16];
      half8_t bf = *(const half8_t*)&bp[ks * 16];
      C = __builtin_amdgcn_mfma_f32_32x32x16_f16(af, bf, C, 0, 0, 0);
    }
    colg = colt * 32 + rw;
    lbv = lb_s[colg];
    lbv_valid = 1;
  }
  __syncthreads();  // all vs reads done -> safe to overwrite as outbuf
  if (lbv_valid && colg < 40) {
    const int rowt = (t >> 6) >> 1;
    const int hi = (t & 63) >> 5;
#pragma unroll
    for (int q = 0; q < 16; ++q) {
      int row = (q & 3) + 8 * (q >> 2) + 4 * hi;  // C/D layout (m74/m101)
      outbuf[(rowt * 32 + row) * 68 + colg] = C[q] + lbv;
    }
  }
  __syncthreads();

  // softmax: node = t>>3, 5 classes per lane
  const int node = t >> 3;
  const int cg = (t & 7) * 5;
  const int n = n0 + node;
  float lg[5];
#pragma unroll
  for (int j = 0; j < 5; ++j) lg[j] = outbuf[node * 68 + cg + j];
  float mx = lg[0];
#pragma unroll
  for (int j = 1; j < 5; ++j) mx = fmaxf(mx, lg[j]);
  mx = fmaxf(mx, __shfl_xor(mx, 1));
  mx = fmaxf(mx, __shfl_xor(mx, 2));
  mx = fmaxf(mx, __shfl_xor(mx, 4));
  float ssum = 0.f;
#pragma unroll
  for (int j = 0; j < 5; ++j) ssum += expf(lg[j] - mx);
  ssum += __shfl_xor(ssum, 1);
  ssum += __shfl_xor(ssum, 2);
  ssum += __shfl_xor(ssum, 4);
  float lse = mx + logf(ssum);
  if (n < N_NODES) {
#pragma unroll
    for (int j = 0; j < 5; ++j) out[(size_t)n * 40 + cg + j] = lg[j] - lse;
  }
}

extern "C" void kernel_launch(void* const* d_in, const int* in_sizes, int n_in,
                              void* d_out, int out_size, void* d_ws, size_t ws_size,
                              hipStream_t stream) {
  const float* x    = (const float*)d_in[0];
  const int*   ei   = (const int*)d_in[1];
  const float* W1   = (const float*)d_in[2];
  const float* b1   = (const float*)d_in[3];
  const float* linW = (const float*)d_in[4];
  const float* linb = (const float*)d_in[5];
  float* out = (float*)d_out;
  char* ws = (char*)d_ws;

  int*    btot   = (int*)(ws + OFF_BTOT);
  int*    bbase  = (int*)(ws + OFF_BBASE);
  __half* hs     = (__half*)(ws + OFF_HS);
  __half* Wt     = (__half*)(ws + OFF_WT);
  __half* WlT    = (__half*)(ws + OFF_WLT);
  int*    ghist  = (int*)(ws + OFF_GHIST);
  int*    gchoff = (int*)(ws + OFF_GCHOFF);
  int*    dump   = (int*)(ws + OFF_DUMP);

  k_hist<<<NB_HIST + 17, 256, 0, stream>>>(ei, ghist, W1, Wt, linW, WlT);
  k_bucket_scan<<<NBUCK, 256, 0, stream>>>(ghist, gchoff, btot);
  k_scan_tot<<<1, 1024, 0, stream>>>(btot, bbase);
  k_bin<<<NB_BIN, 512, 0, stream>>>(ei, bbase, gchoff, dump);
  k_gemm1<<<NBUCK, 256, 0, stream>>>(x, Wt, dump, bbase, hs);
  k_aggfin<<<NBUCK, 512, 0, stream>>>(hs, dump, bbase, b1, WlT, linb, out);
}

// Round 14
// 107.013 us; speedup vs baseline: 2.1055x; 1.2290x over previous
//
#include <hip/hip_runtime.h>
#include <hip/hip_fp16.h>
#include <math.h>

#define N_NODES 100000
#define N_EDGES 1600000
#define NBUCK   1563          // ceil(100000/64) buckets of 64 dst nodes
#define NBUCK_P 1568          // padded row length for hist tables
#define NB_HIST 256           // hist blocks (slice 6250)
#define NB_BIN  256           // bin blocks (slice 6250, same rows as hist)

// ws layout (bytes)
#define OFF_BTOT   0x1000u     // int[NBUCK_P] bucket totals
#define OFF_BBASE  0x5000u     // int[NBUCK+1] scan of totals (dump base, exact)
#define OFF_HS     0x780000u   // fp8[N_NODES*128] (12.8 MB)
#define OFF_WT     0x2100000u  // __half[128*128] fp16 W1^T (32 KB)
#define OFF_WLT    0x2110000u  // __half[64*128]  fp16 linW^T, class-padded (16 KB)
#define OFF_GHIST  0x3980000u  // int[NB_HIST*NBUCK_P]  (1.6 MB)
#define OFF_GCHOFF 0x3B10000u  // int[NB_BIN*NBUCK_P]   (1.6 MB)
#define OFF_DUMP   0x3CA0000u  // int[N_EDGES] packed (6.4 MB, ends 0x42C0000)

typedef _Float16 half8_t __attribute__((ext_vector_type(8)));
typedef float f32x2_t __attribute__((ext_vector_type(2)));
typedef float f32x4_t __attribute__((ext_vector_type(4)));
typedef float f32x16_t __attribute__((ext_vector_type(16)));

// blocks [0,255]: per-block bucket histogram of dst (inline dtype detect).
// blocks [256,271]: W1 (f32 [128k][128n]) -> Wt fp16 [128n][128k].
// block  272:       linW (f32 [128k][40c]) -> WlT fp16 [64c][128k] (pad c>=40 = 0).
__global__ __launch_bounds__(256) void k_hist(const int* __restrict__ p32,
                                              int* __restrict__ G_hist,
                                              const float* __restrict__ W,
                                              __half* __restrict__ Wt,
                                              const float* __restrict__ linW,
                                              __half* __restrict__ WlT) {
  const int t = threadIdx.x;
  if (blockIdx.x == NB_HIST + 16) {  // ---- linW transpose ----
    __shared__ float buf[5120];
#pragma unroll
    for (int i = 0; i < 5; ++i) {
      int lin = i * 256 + t;  // 1280 float4s = 5120 floats
      ((float4*)buf)[lin] = ((const float4*)linW)[lin];
    }
    __syncthreads();
#pragma unroll
    for (int i = 0; i < 4; ++i) {
      int lin = i * 256 + t;  // 1024 int4s = 64 rows x 16
      int c = lin >> 4, kb = lin & 15;
      union { __half h[8]; int4 v; } u;
#pragma unroll
      for (int q = 0; q < 8; ++q)
        u.h[q] = (c < 40) ? __float2half(buf[(kb * 8 + q) * 40 + c])
                          : __float2half(0.f);
      *(int4*)&WlT[(size_t)c * 128 + kb * 8] = u.v;
    }
    return;
  }
  if (blockIdx.x >= NB_HIST) {  // ---- W1 transpose ----
    __shared__ float buf1[1024];
    const int b = blockIdx.x - NB_HIST;
    float4 v = ((const float4*)(W + (size_t)b * 1024))[t];
    *(float4*)&buf1[t * 4] = v;
    __syncthreads();
    if (t < 128) {
      union { __half h[8]; int4 v; } u;
#pragma unroll
      for (int k = 0; k < 8; ++k) u.h[k] = __float2half(buf1[k * 128 + t]);
      *(int4*)&Wt[(size_t)t * 128 + b * 8] = u.v;
    }
    return;
  }
  __shared__ int hist[NBUCK];
  __shared__ int nz;
  if (t == 0) nz = 0;
  for (int i = t; i < NBUCK; i += 256) hist[i] = 0;
  __syncthreads();
  if (p32[2 * t + 1] != 0) atomicAdd(&nz, 1);
  __syncthreads();
  const int s = (nz == 0) ? 1 : 0;  // 1 => int64 (stride 2)
  const int base = blockIdx.x * 6250;
  for (int i = 0; i < 25; ++i) {
    int e = base + i * 256 + t;
    if (e < base + 6250) {
      int c = p32[((size_t)(N_EDGES + e)) << s];
      atomicAdd(&hist[c >> 6], 1);
    }
  }
  __syncthreads();
  for (int i = t; i < NBUCK; i += 256) G_hist[blockIdx.x * NBUCK_P + i] = hist[i];
}

// per bucket: scan 256 exact chunk sizes -> per-binblock offsets + total
__global__ __launch_bounds__(256) void k_bucket_scan(const int* __restrict__ G_hist,
                                                     int* __restrict__ G_choff,
                                                     int* __restrict__ btot) {
  __shared__ int wsum[4];
  const int t = threadIdx.x;
  const int b = blockIdx.x;
  const int c = G_hist[t * NBUCK_P + b];
  int sv = c;
  const int lane = t & 63;
  for (int d = 1; d < 64; d <<= 1) {
    int a = __shfl_up(sv, d);
    if (lane >= d) sv += a;
  }
  if (lane == 63) wsum[t >> 6] = sv;
  __syncthreads();
  int o = 0;
  for (int w2 = 0; w2 < (t >> 6); ++w2) o += wsum[w2];
  G_choff[t * NBUCK_P + b] = o + sv - c;  // exclusive offset within bucket
  if (t == 255) btot[b] = o + sv;
}

// scan 1563 totals -> bbase[0..NBUCK] (exclusive), 1 block
__global__ __launch_bounds__(1024) void k_scan_tot(const int* __restrict__ tot,
                                                   int* __restrict__ base) {
  __shared__ int sm[1024];
  const int t = threadIdx.x;
  int a = (2 * t < NBUCK) ? tot[2 * t] : 0;
  int bb = (2 * t + 1 < NBUCK) ? tot[2 * t + 1] : 0;
  int pair = a + bb;
  sm[t] = pair;
  __syncthreads();
  for (int off = 1; off < 1024; off <<= 1) {
    int x = (t >= off) ? sm[t - off] : 0;
    __syncthreads();
    sm[t] += x;
    __syncthreads();
  }
  int S = sm[t];
  if (2 * t <= NBUCK) base[2 * t] = S - pair;
  if (2 * t + 1 <= NBUCK) base[2 * t + 1] = S - bb;
}

// place packed (src<<6|ldst) records into block-private chunks (no global atomics)
__global__ __launch_bounds__(512) void k_bin(const int* __restrict__ p32,
                                             const int* __restrict__ bbase,
                                             const int* __restrict__ G_choff,
                                             int* __restrict__ dump) {
  __shared__ int gb[NBUCK];
  __shared__ int cur[NBUCK];
  __shared__ int nz;
  const int t = threadIdx.x;
  const int blk = blockIdx.x;
  if (t == 0) nz = 0;
  for (int i = t; i < NBUCK; i += 512) {
    gb[i] = bbase[i] + G_choff[blk * NBUCK_P + i];
    cur[i] = 0;
  }
  __syncthreads();
  if (t < 256 && p32[2 * t + 1] != 0) atomicAdd(&nz, 1);
  __syncthreads();
  const int s = (nz == 0) ? 1 : 0;
  const int base = blk * 6250;
  for (int i = 0; i < 13; ++i) {
    int e = base + i * 512 + t;
    if (e < base + 6250) {
      int r = p32[((size_t)e) << s];
      int c = p32[((size_t)(N_EDGES + e)) << s];
      int bk = c >> 6;
      int p = atomicAdd(&cur[bk], 1);
      dump[gb[bk] + p] = (r << 6) | (c & 63);
    }
  }
}

// hs[n] = fp8_e4m3( rsqrt(deg[n]+1) * (x @ W1)[n] )  via MFMA f16.
// deg computed in-block from this bucket's dump chunk (block b == bucket b).
__global__ __launch_bounds__(256, 3) void k_gemm1(
    const float* __restrict__ x, const __half* __restrict__ Wt,
    const int* __restrict__ dump, const int* __restrict__ bbase,
    unsigned char* __restrict__ hs8) {
  __shared__ _Float16 xt[64 * 136];
  __shared__ _Float16 wt[128 * 136];
  __shared__ int c_s[64];
  const int t = threadIdx.x;
  const int b = blockIdx.x;
  const int row0 = b * 64;
  if (t < 64) c_s[t] = 0;
  __syncthreads();
#pragma unroll
  for (int i = 0; i < 8; ++i) {
    int lin = i * 256 + t;
    int r = lin >> 5, c4 = lin & 31;
    int gr = row0 + r;
    float4 v = make_float4(0.f, 0.f, 0.f, 0.f);
    if (gr < N_NODES) v = *(const float4*)(x + (size_t)gr * 128 + c4 * 4);
    union { __half2 h2[2]; int2 iv; } u;
    u.h2[0] = __floats2half2_rn(v.x, v.y);
    u.h2[1] = __floats2half2_rn(v.z, v.w);
    *(int2*)&xt[r * 136 + c4 * 4] = u.iv;
  }
#pragma unroll
  for (int i = 0; i < 8; ++i) {
    int lin = i * 256 + t;
    int n = lin >> 4, kb = lin & 15;
    int4 v = *(const int4*)(Wt + (size_t)n * 128 + kb * 8);
    *(int4*)&wt[n * 136 + kb * 8] = v;
  }
  {
    const int rb = bbase[b];
    const int m = bbase[b + 1] - rb;
    for (int j = t; j < m; j += 256) atomicAdd(&c_s[dump[rb + j] & 63], 1);
  }
  __syncthreads();

  const int w = t >> 6, l = t & 63;
  const int r = l & 15, g = l >> 4;
  const _Float16* ap = &xt[(w * 16 + r) * 136 + g * 8];
  half8_t af[4];
#pragma unroll
  for (int ks = 0; ks < 4; ++ks) af[ks] = *(const half8_t*)&ap[ks * 32];

  const int lbase = w * 16 + g * 4;
  const int rbase = row0 + lbase;
  float dv[4];
#pragma unroll
  for (int j = 0; j < 4; ++j)
    dv[j] = rsqrtf((float)c_s[lbase + j] + 1.0f);

#pragma unroll
  for (int ct = 0; ct < 8; ++ct) {
    f32x4_t acc = {0.f, 0.f, 0.f, 0.f};
    const _Float16* bp = &wt[(ct * 16 + r) * 136 + g * 8];
#pragma unroll
    for (int ks = 0; ks < 4; ++ks) {
      half8_t bf = *(const half8_t*)&bp[ks * 32];
      acc = __builtin_amdgcn_mfma_f32_16x16x32_f16(af[ks], bf, acc, 0, 0, 0);
    }
#pragma unroll
    for (int j = 0; j < 4; ++j) {
      int rr = rbase + j;
      if (rr < N_NODES) {
        unsigned int pk =
            __builtin_amdgcn_cvt_pk_fp8_f32(acc[j] * dv[j], 0.f, 0u, false);
        hs8[(size_t)rr * 128 + ct * 16 + r] = (unsigned char)(pk & 0xffu);
      }
    }
  }
}

// fully fused per bucket (64 nodes, 512 threads):
// local deg + CSR placement (from dump, 2 passes) -> fp8 gather-aggregate
// (f32 accum) -> relu'd fp16 rows in LDS -> MFMA Linear -> log_softmax -> out.
__global__ __launch_bounds__(512, 8) void k_aggfin(
    const unsigned char* __restrict__ hs8, const int* __restrict__ dump,
    const int* __restrict__ bbase, const float* __restrict__ b1,
    const __half* __restrict__ WlT, const float* __restrict__ linb,
    float* __restrict__ out) {
  __shared__ int stage[4352];          // 17408 B; alias vs[64][136] f16, outbuf[64][68] f32
  __shared__ _Float16 wlt[64 * 136];   // 17408 B
  __shared__ float lb_s[64];
  __shared__ int cnt_s[64];
  __shared__ int off_s[64];
  __shared__ int cur_s[64];
  _Float16* vs = (_Float16*)stage;
  float* outbuf = (float*)stage;

  const int t = threadIdx.x;
  const int b = blockIdx.x;
  const int n0 = b << 6;
  if (t < 64) cnt_s[t] = 0;
#pragma unroll
  for (int i = 0; i < 2; ++i) {
    int lin = i * 512 + t;  // 1024 int4s = 64 rows x 16
    int c = lin >> 4, kb = lin & 15;
    int4 v = *(const int4*)(WlT + (size_t)c * 128 + kb * 8);
    *(int4*)&wlt[c * 136 + kb * 8] = v;
  }
  if (t < 64) lb_s[t] = (t < 40) ? linb[t] : 0.f;
  __syncthreads();

  const int rb = bbase[b];
  const int m = bbase[b + 1] - rb;
  // pass 1: degree count
  for (int j = t; j < m; j += 512) atomicAdd(&cnt_s[dump[rb + j] & 63], 1);
  __syncthreads();
  if (t < 64) {
    int v = cnt_s[t];
    int sv = v;
    for (int d = 1; d < 64; d <<= 1) {
      int u = __shfl_up(sv, d);
      if (t >= d) sv += u;
    }
    off_s[t] = sv - v;
    cur_s[t] = sv - v;
  }
  __syncthreads();
  // pass 2: place src indices grouped by dst
  for (int j = t; j < m; j += 512) {
    int rec = dump[rb + j];
    int p = atomicAdd(&cur_s[rec & 63], 1);
    stage[p] = rec >> 6;
  }
  __syncthreads();

  // gather-aggregate: half-wave hw handles nodes hw, hw+16, hw+32, hw+48.
  // Each lane owns cols lane*4..lane*4+3 (4 fp8 bytes = 1 dword per row).
  const int hw = t >> 5, lane = t & 31;
  uint2 res[4];
#pragma unroll
  for (int mi = 0; mi < 4; ++mi) {
    res[mi] = make_uint2(0u, 0u);
    const int i = hw + mi * 16;
    const int n = n0 + i;
    if (n >= N_NODES) continue;
    float4 sum;
    {
      unsigned int raw = *(const unsigned int*)(hs8 + (size_t)n * 128 + lane * 4);
      f32x2_t lo = __builtin_amdgcn_cvt_pk_f32_fp8(raw, false);
      f32x2_t hi = __builtin_amdgcn_cvt_pk_f32_fp8(raw, true);
      sum = make_float4(lo[0], lo[1], hi[0], hi[1]);  // self-loop
    }
    int j = off_s[i];
    const int e0 = off_s[i] + cnt_s[i];
    for (; j + 8 <= e0; j += 8) {
      unsigned int r[8];
#pragma unroll
      for (int q = 0; q < 8; ++q) {
        int src = stage[j + q];
        r[q] = *(const unsigned int*)(hs8 + (size_t)src * 128 + lane * 4);
      }
#pragma unroll
      for (int q = 0; q < 8; ++q) {
        f32x2_t lo = __builtin_amdgcn_cvt_pk_f32_fp8(r[q], false);
        f32x2_t hi = __builtin_amdgcn_cvt_pk_f32_fp8(r[q], true);
        sum.x += lo[0]; sum.y += lo[1]; sum.z += hi[0]; sum.w += hi[1];
      }
    }
    if (j + 4 <= e0) {
      unsigned int r[4];
#pragma unroll
      for (int q = 0; q < 4; ++q) {
        int src = stage[j + q];
        r[q] = *(const unsigned int*)(hs8 + (size_t)src * 128 + lane * 4);
      }
#pragma unroll
      for (int q = 0; q < 4; ++q) {
        f32x2_t lo = __builtin_amdgcn_cvt_pk_f32_fp8(r[q], false);
        f32x2_t hi = __builtin_amdgcn_cvt_pk_f32_fp8(r[q], true);
        sum.x += lo[0]; sum.y += lo[1]; sum.z += hi[0]; sum.w += hi[1];
      }
      j += 4;
    }
    for (; j < e0; ++j) {
      int src = stage[j];
      unsigned int raw = *(const unsigned int*)(hs8 + (size_t)src * 128 + lane * 4);
      f32x2_t lo = __builtin_amdgcn_cvt_pk_f32_fp8(raw, false);
      f32x2_t hi = __builtin_amdgcn_cvt_pk_f32_fp8(raw, true);
      sum.x += lo[0]; sum.y += lo[1]; sum.z += hi[0]; sum.w += hi[1];
    }
    float d = rsqrtf((float)cnt_s[i] + 1.0f);
    float4 bb = *(const float4*)(b1 + lane * 4);
    union { __half2 h[2]; uint2 v; } u;
    u.h[0] = __floats2half2_rn(fmaxf(fmaf(d, sum.x, bb.x), 0.f),
                               fmaxf(fmaf(d, sum.y, bb.y), 0.f));
    u.h[1] = __floats2half2_rn(fmaxf(fmaf(d, sum.z, bb.z), 0.f),
                               fmaxf(fmaf(d, sum.w, bb.w), 0.f));
    res[mi] = u.v;
  }
  __syncthreads();  // stage (records) dead -> reuse as vs
#pragma unroll
  for (int mi = 0; mi < 4; ++mi) {
    const int i = hw + mi * 16;
    *(uint2*)&vs[i * 136 + lane * 4] = res[mi];
  }
  __syncthreads();

  // MFMA Linear: vs[64x128] @ wlt^T -> logits 64x64 (cols>=40 ignored).
  const int wv = t >> 6, l64 = t & 63;
  f32x16_t C = {};
  int colg = 0, lbv_valid = 0;
  float lbv = 0.f;
  if (wv < 4) {
    const int rowt = wv >> 1, colt = wv & 1;
    const int rw = l64 & 31, kg = l64 >> 5;  // kg in {0,1}
    const _Float16* ap = &vs[(rowt * 32 + rw) * 136 + kg * 8];
    const _Float16* bp = &wlt[(colt * 32 + rw) * 136 + kg * 8];
#pragma unroll
    for (int ks = 0; ks < 8; ++ks) {
      half8_t af = *(const half8_t*)&ap[ks * 16];
      half8_t bf = *(const half8_t*)&bp[ks * 16];
      C = __builtin_amdgcn_mfma_f32_32x32x16_f16(af, bf, C, 0, 0, 0);
    }
    colg = colt * 32 + rw;
    lbv = lb_s[colg];
    lbv_valid = 1;
  }
  __syncthreads();  // all vs reads done -> safe to overwrite as outbuf
  if (lbv_valid && colg < 40) {
    const int rowt = (t >> 6) >> 1;
    const int hi = (t & 63) >> 5;
#pragma unroll
    for (int q = 0; q < 16; ++q) {
      int row = (q & 3) + 8 * (q >> 2) + 4 * hi;  // C/D layout (m74/m101)
      outbuf[(rowt * 32 + row) * 68 + colg] = C[q] + lbv;
    }
  }
  __syncthreads();

  // softmax: node = t>>3, 5 classes per lane
  const int node = t >> 3;
  const int cg = (t & 7) * 5;
  const int n = n0 + node;
  float lg[5];
#pragma unroll
  for (int j = 0; j < 5; ++j) lg[j] = outbuf[node * 68 + cg + j];
  float mx = lg[0];
#pragma unroll
  for (int j = 1; j < 5; ++j) mx = fmaxf(mx, lg[j]);
  mx = fmaxf(mx, __shfl_xor(mx, 1));
  mx = fmaxf(mx, __shfl_xor(mx, 2));
  mx = fmaxf(mx, __shfl_xor(mx, 4));
  float ssum = 0.f;
#pragma unroll
  for (int j = 0; j < 5; ++j) ssum += expf(lg[j] - mx);
  ssum += __shfl_xor(ssum, 1);
  ssum += __shfl_xor(ssum, 2);
  ssum += __shfl_xor(ssum, 4);
  float lse = mx + logf(ssum);
  if (n < N_NODES) {
#pragma unroll
    for (int j = 0; j < 5; ++j) out[(size_t)n * 40 + cg + j] = lg[j] - lse;
  }
}

extern "C" void kernel_launch(void* const* d_in, const int* in_sizes, int n_in,
                              void* d_out, int out_size, void* d_ws, size_t ws_size,
                              hipStream_t stream) {
  const float* x    = (const float*)d_in[0];
  const int*   ei   = (const int*)d_in[1];
  const float* W1   = (const float*)d_in[2];
  const float* b1   = (const float*)d_in[3];
  const float* linW = (const float*)d_in[4];
  const float* linb = (const float*)d_in[5];
  float* out = (float*)d_out;
  char* ws = (char*)d_ws;

  int*           btot   = (int*)(ws + OFF_BTOT);
  int*           bbase  = (int*)(ws + OFF_BBASE);
  unsigned char* hs8    = (unsigned char*)(ws + OFF_HS);
  __half*        Wt     = (__half*)(ws + OFF_WT);
  __half*        WlT    = (__half*)(ws + OFF_WLT);
  int*           ghist  = (int*)(ws + OFF_GHIST);
  int*           gchoff = (int*)(ws + OFF_GCHOFF);
  int*           dump   = (int*)(ws + OFF_DUMP);

  k_hist<<<NB_HIST + 17, 256, 0, stream>>>(ei, ghist, W1, Wt, linW, WlT);
  k_bucket_scan<<<NBUCK, 256, 0, stream>>>(ghist, gchoff, btot);
  k_scan_tot<<<1, 1024, 0, stream>>>(btot, bbase);
  k_bin<<<NB_BIN, 512, 0, stream>>>(ei, bbase, gchoff, dump);
  k_gemm1<<<NBUCK, 256, 0, stream>>>(x, Wt, dump, bbase, hs8);
  k_aggfin<<<NBUCK, 512, 0, stream>>>(hs8, dump, bbase, b1, WlT, linb, out);
}

// Round 15
// 104.488 us; speedup vs baseline: 2.1564x; 1.0242x over previous
//
#include <hip/hip_runtime.h>
#include <hip/hip_fp16.h>
#include <math.h>

#define N_NODES 100000
#define N_EDGES 1600000
#define NBUCK   1563          // ceil(100000/64) buckets of 64 dst nodes
#define NBUCK_P 1568          // padded row length for hist tables
#define NB_HIST 256           // hist blocks (slice 6250)
#define NB_BIN  256           // bin blocks (slice 6250, same rows as hist)
#define DCAP    1536          // fixed dump capacity per bucket (max ~1136 + 12 sigma)

// ws layout (bytes)
#define OFF_BTOT   0x1000u     // int[NBUCK_P] bucket totals (record count m)
#define OFF_HS     0x780000u   // fp8[N_NODES*128] (12.8 MB)
#define OFF_WT     0x2100000u  // __half[128*128] fp16 W1^T (32 KB)
#define OFF_WLT    0x2110000u  // __half[64*128]  fp16 linW^T, class-padded (16 KB)
#define OFF_GHIST  0x3980000u  // int[NB_HIST*NBUCK_P]  (1.6 MB)
#define OFF_GCHOFF 0x3B10000u  // int[NB_BIN*NBUCK_P]   (1.6 MB)
#define OFF_DUMP   0x3CA0000u  // int[NBUCK*DCAP] packed (9.6 MB, ends ~0x4660000)

typedef _Float16 half8_t __attribute__((ext_vector_type(8)));
typedef float f32x2_t __attribute__((ext_vector_type(2)));
typedef float f32x4_t __attribute__((ext_vector_type(4)));
typedef float f32x16_t __attribute__((ext_vector_type(16)));

// blocks [0,255]: per-block bucket histogram of dst (inline dtype detect).
// blocks [256,271]: W1 (f32 [128k][128n]) -> Wt fp16 [128n][128k].
// block  272:       linW (f32 [128k][40c]) -> WlT fp16 [64c][128k] (pad c>=40 = 0).
__global__ __launch_bounds__(256) void k_hist(const int* __restrict__ p32,
                                              int* __restrict__ G_hist,
                                              const float* __restrict__ W,
                                              __half* __restrict__ Wt,
                                              const float* __restrict__ linW,
                                              __half* __restrict__ WlT) {
  const int t = threadIdx.x;
  if (blockIdx.x == NB_HIST + 16) {  // ---- linW transpose ----
    __shared__ float buf[5120];
#pragma unroll
    for (int i = 0; i < 5; ++i) {
      int lin = i * 256 + t;  // 1280 float4s = 5120 floats
      ((float4*)buf)[lin] = ((const float4*)linW)[lin];
    }
    __syncthreads();
#pragma unroll
    for (int i = 0; i < 4; ++i) {
      int lin = i * 256 + t;  // 1024 int4s = 64 rows x 16
      int c = lin >> 4, kb = lin & 15;
      union { __half h[8]; int4 v; } u;
#pragma unroll
      for (int q = 0; q < 8; ++q)
        u.h[q] = (c < 40) ? __float2half(buf[(kb * 8 + q) * 40 + c])
                          : __float2half(0.f);
      *(int4*)&WlT[(size_t)c * 128 + kb * 8] = u.v;
    }
    return;
  }
  if (blockIdx.x >= NB_HIST) {  // ---- W1 transpose ----
    __shared__ float buf1[1024];
    const int b = blockIdx.x - NB_HIST;
    float4 v = ((const float4*)(W + (size_t)b * 1024))[t];
    *(float4*)&buf1[t * 4] = v;
    __syncthreads();
    if (t < 128) {
      union { __half h[8]; int4 v; } u;
#pragma unroll
      for (int k = 0; k < 8; ++k) u.h[k] = __float2half(buf1[k * 128 + t]);
      *(int4*)&Wt[(size_t)t * 128 + b * 8] = u.v;
    }
    return;
  }
  __shared__ int hist[NBUCK];
  __shared__ int nz;
  if (t == 0) nz = 0;
  for (int i = t; i < NBUCK; i += 256) hist[i] = 0;
  __syncthreads();
  if (p32[2 * t + 1] != 0) atomicAdd(&nz, 1);
  __syncthreads();
  const int s = (nz == 0) ? 1 : 0;  // 1 => int64 (stride 2)
  const int base = blockIdx.x * 6250;
  for (int i = 0; i < 25; ++i) {
    int e = base + i * 256 + t;
    if (e < base + 6250) {
      int c = p32[((size_t)(N_EDGES + e)) << s];
      atomicAdd(&hist[c >> 6], 1);
    }
  }
  __syncthreads();
  for (int i = t; i < NBUCK; i += 256) G_hist[blockIdx.x * NBUCK_P + i] = hist[i];
}

// per bucket: scan 256 exact chunk sizes -> per-binblock offsets + total (= m)
__global__ __launch_bounds__(256) void k_bucket_scan(const int* __restrict__ G_hist,
                                                     int* __restrict__ G_choff,
                                                     int* __restrict__ btot) {
  __shared__ int wsum[4];
  const int t = threadIdx.x;
  const int b = blockIdx.x;
  const int c = G_hist[t * NBUCK_P + b];
  int sv = c;
  const int lane = t & 63;
  for (int d = 1; d < 64; d <<= 1) {
    int a = __shfl_up(sv, d);
    if (lane >= d) sv += a;
  }
  if (lane == 63) wsum[t >> 6] = sv;
  __syncthreads();
  int o = 0;
  for (int w2 = 0; w2 < (t >> 6); ++w2) o += wsum[w2];
  G_choff[t * NBUCK_P + b] = o + sv - c;  // exclusive offset within bucket
  if (t == 255) btot[b] = o + sv;
}

// place packed (src<<6|ldst) records into block-private chunks at fixed bases
__global__ __launch_bounds__(512) void k_bin(const int* __restrict__ p32,
                                             const int* __restrict__ G_choff,
                                             int* __restrict__ dump) {
  __shared__ int gb[NBUCK];
  __shared__ int cur[NBUCK];
  __shared__ int nz;
  const int t = threadIdx.x;
  const int blk = blockIdx.x;
  if (t == 0) nz = 0;
  for (int i = t; i < NBUCK; i += 512) {
    gb[i] = i * DCAP + G_choff[blk * NBUCK_P + i];
    cur[i] = 0;
  }
  __syncthreads();
  if (t < 256 && p32[2 * t + 1] != 0) atomicAdd(&nz, 1);
  __syncthreads();
  const int s = (nz == 0) ? 1 : 0;
  const int base = blk * 6250;
  for (int i = 0; i < 13; ++i) {
    int e = base + i * 512 + t;
    if (e < base + 6250) {
      int r = p32[((size_t)e) << s];
      int c = p32[((size_t)(N_EDGES + e)) << s];
      int bk = c >> 6;
      int p = atomicAdd(&cur[bk], 1);
      dump[gb[bk] + p] = (r << 6) | (c & 63);
    }
  }
}

// hs[n] = fp8_e4m3( rsqrt(deg[n]+1) * (x @ W1)[n] )  via MFMA f16.
// deg computed in-block from this bucket's dump chunk (block b == bucket b).
__global__ __launch_bounds__(256, 3) void k_gemm1(
    const float* __restrict__ x, const __half* __restrict__ Wt,
    const int* __restrict__ dump, const int* __restrict__ btot,
    unsigned char* __restrict__ hs8) {
  __shared__ _Float16 xt[64 * 136];
  __shared__ _Float16 wt[128 * 136];
  __shared__ int c_s[64];
  const int t = threadIdx.x;
  const int b = blockIdx.x;
  const int row0 = b * 64;
  if (t < 64) c_s[t] = 0;
  __syncthreads();
#pragma unroll
  for (int i = 0; i < 8; ++i) {
    int lin = i * 256 + t;
    int r = lin >> 5, c4 = lin & 31;
    int gr = row0 + r;
    float4 v = make_float4(0.f, 0.f, 0.f, 0.f);
    if (gr < N_NODES) v = *(const float4*)(x + (size_t)gr * 128 + c4 * 4);
    union { __half2 h2[2]; int2 iv; } u;
    u.h2[0] = __floats2half2_rn(v.x, v.y);
    u.h2[1] = __floats2half2_rn(v.z, v.w);
    *(int2*)&xt[r * 136 + c4 * 4] = u.iv;
  }
#pragma unroll
  for (int i = 0; i < 8; ++i) {
    int lin = i * 256 + t;
    int n = lin >> 4, kb = lin & 15;
    int4 v = *(const int4*)(Wt + (size_t)n * 128 + kb * 8);
    *(int4*)&wt[n * 136 + kb * 8] = v;
  }
  {
    const int rb = b * DCAP;
    const int m = btot[b];
    for (int j = t; j < m; j += 256) atomicAdd(&c_s[dump[rb + j] & 63], 1);
  }
  __syncthreads();

  const int w = t >> 6, l = t & 63;
  const int r = l & 15, g = l >> 4;
  const _Float16* ap = &xt[(w * 16 + r) * 136 + g * 8];
  half8_t af[4];
#pragma unroll
  for (int ks = 0; ks < 4; ++ks) af[ks] = *(const half8_t*)&ap[ks * 32];

  const int lbase = w * 16 + g * 4;
  const int rbase = row0 + lbase;
  float dv[4];
#pragma unroll
  for (int j = 0; j < 4; ++j)
    dv[j] = rsqrtf((float)c_s[lbase + j] + 1.0f);

#pragma unroll
  for (int ct = 0; ct < 8; ++ct) {
    f32x4_t acc = {0.f, 0.f, 0.f, 0.f};
    const _Float16* bp = &wt[(ct * 16 + r) * 136 + g * 8];
#pragma unroll
    for (int ks = 0; ks < 4; ++ks) {
      half8_t bf = *(const half8_t*)&bp[ks * 32];
      acc = __builtin_amdgcn_mfma_f32_16x16x32_f16(af[ks], bf, acc, 0, 0, 0);
    }
#pragma unroll
    for (int j = 0; j < 4; ++j) {
      int rr = rbase + j;
      if (rr < N_NODES) {
        unsigned int pk =
            __builtin_amdgcn_cvt_pk_fp8_f32(acc[j] * dv[j], 0.f, 0u, false);
        hs8[(size_t)rr * 128 + ct * 16 + r] = (unsigned char)(pk & 0xffu);
      }
    }
  }
}

// fully fused per bucket (64 nodes, 512 threads):
// local deg + CSR placement -> fp8 gather-aggregate (f32x4 pk_add accum) ->
// relu'd fp16 rows in LDS -> MFMA Linear -> log_softmax -> out.
__global__ __launch_bounds__(512, 8) void k_aggfin(
    const unsigned char* __restrict__ hs8, const int* __restrict__ dump,
    const int* __restrict__ btot, const float* __restrict__ b1,
    const __half* __restrict__ WlT, const float* __restrict__ linb,
    float* __restrict__ out) {
  __shared__ int stage[4352];          // 17408 B; alias vs[64][136] f16, outbuf[64][68] f32
  __shared__ _Float16 wlt[64 * 136];   // 17408 B
  __shared__ float lb_s[64];
  __shared__ int cnt_s[64];
  __shared__ int off_s[64];
  __shared__ int cur_s[64];
  _Float16* vs = (_Float16*)stage;
  float* outbuf = (float*)stage;

  const int t = threadIdx.x;
  const int b = blockIdx.x;
  const int n0 = b << 6;
  if (t < 64) cnt_s[t] = 0;
#pragma unroll
  for (int i = 0; i < 2; ++i) {
    int lin = i * 512 + t;  // 1024 int4s = 64 rows x 16
    int c = lin >> 4, kb = lin & 15;
    int4 v = *(const int4*)(WlT + (size_t)c * 128 + kb * 8);
    *(int4*)&wlt[c * 136 + kb * 8] = v;
  }
  if (t < 64) lb_s[t] = (t < 40) ? linb[t] : 0.f;
  __syncthreads();

  const int rb = b * DCAP;
  const int m = btot[b];
  // pass 1: degree count
  for (int j = t; j < m; j += 512) atomicAdd(&cnt_s[dump[rb + j] & 63], 1);
  __syncthreads();
  if (t < 64) {
    int v = cnt_s[t];
    int sv = v;
    for (int d = 1; d < 64; d <<= 1) {
      int u = __shfl_up(sv, d);
      if (t >= d) sv += u;
    }
    off_s[t] = sv - v;
    cur_s[t] = sv - v;
  }
  __syncthreads();
  // pass 2: place src indices grouped by dst
  for (int j = t; j < m; j += 512) {
    int rec = dump[rb + j];
    int p = atomicAdd(&cur_s[rec & 63], 1);
    stage[p] = rec >> 6;
  }
  __syncthreads();

  // gather-aggregate: half-wave hw handles nodes hw, hw+16, hw+32, hw+48.
  // Each lane owns cols lane*4..lane*4+3 (4 fp8 bytes = 1 dword per row).
  const int hw = t >> 5, lane = t & 31;
  uint2 res[4];
#pragma unroll
  for (int mi = 0; mi < 4; ++mi) {
    res[mi] = make_uint2(0u, 0u);
    const int i = hw + mi * 16;
    const int n = n0 + i;
    if (n >= N_NODES) continue;
    f32x4_t sum;
    {
      unsigned int raw = *(const unsigned int*)(hs8 + (size_t)n * 128 + lane * 4);
      f32x2_t lo = __builtin_amdgcn_cvt_pk_f32_fp8(raw, false);
      f32x2_t hi = __builtin_amdgcn_cvt_pk_f32_fp8(raw, true);
      sum[0] = lo[0]; sum[1] = lo[1]; sum[2] = hi[0]; sum[3] = hi[1];  // self-loop
    }
    int j = off_s[i];
    const int e0 = off_s[i] + cnt_s[i];
    for (; j + 8 <= e0; j += 8) {
      unsigned int r[8];
#pragma unroll
      for (int q = 0; q < 8; ++q) {
        int src = stage[j + q];
        r[q] = *(const unsigned int*)(hs8 + (size_t)src * 128 + lane * 4);
      }
#pragma unroll
      for (int q = 0; q < 8; ++q) {
        f32x2_t lo = __builtin_amdgcn_cvt_pk_f32_fp8(r[q], false);
        f32x2_t hi = __builtin_amdgcn_cvt_pk_f32_fp8(r[q], true);
        f32x4_t v; v[0] = lo[0]; v[1] = lo[1]; v[2] = hi[0]; v[3] = hi[1];
        sum += v;  // v_pk_add_f32 x2
      }
    }
    if (j + 4 <= e0) {
      unsigned int r[4];
#pragma unroll
      for (int q = 0; q < 4; ++q) {
        int src = stage[j + q];
        r[q] = *(const unsigned int*)(hs8 + (size_t)src * 128 + lane * 4);
      }
#pragma unroll
      for (int q = 0; q < 4; ++q) {
        f32x2_t lo = __builtin_amdgcn_cvt_pk_f32_fp8(r[q], false);
        f32x2_t hi = __builtin_amdgcn_cvt_pk_f32_fp8(r[q], true);
        f32x4_t v; v[0] = lo[0]; v[1] = lo[1]; v[2] = hi[0]; v[3] = hi[1];
        sum += v;
      }
      j += 4;
    }
    for (; j < e0; ++j) {
      int src = stage[j];
      unsigned int raw = *(const unsigned int*)(hs8 + (size_t)src * 128 + lane * 4);
      f32x2_t lo = __builtin_amdgcn_cvt_pk_f32_fp8(raw, false);
      f32x2_t hi = __builtin_amdgcn_cvt_pk_f32_fp8(raw, true);
      f32x4_t v; v[0] = lo[0]; v[1] = lo[1]; v[2] = hi[0]; v[3] = hi[1];
      sum += v;
    }
    float d = rsqrtf((float)cnt_s[i] + 1.0f);
    float4 bb = *(const float4*)(b1 + lane * 4);
    union { __half2 h[2]; uint2 v; } u;
    u.h[0] = __floats2half2_rn(fmaxf(fmaf(d, sum[0], bb.x), 0.f),
                               fmaxf(fmaf(d, sum[1], bb.y), 0.f));
    u.h[1] = __floats2half2_rn(fmaxf(fmaf(d, sum[2], bb.z), 0.f),
                               fmaxf(fmaf(d, sum[3], bb.w), 0.f));
    res[mi] = u.v;
  }
  __syncthreads();  // stage (records) dead -> reuse as vs
#pragma unroll
  for (int mi = 0; mi < 4; ++mi) {
    const int i = hw + mi * 16;
    *(uint2*)&vs[i * 136 + lane * 4] = res[mi];
  }
  __syncthreads();

  // MFMA Linear: vs[64x128] @ wlt^T -> logits 64x64 (cols>=40 ignored).
  const int wv = t >> 6, l64 = t & 63;
  f32x16_t C = {};
  int colg = 0, lbv_valid = 0;
  float lbv = 0.f;
  if (wv < 4) {
    const int rowt = wv >> 1, colt = wv & 1;
    const int rw = l64 & 31, kg = l64 >> 5;  // kg in {0,1}
    const _Float16* ap = &vs[(rowt * 32 + rw) * 136 + kg * 8];
    const _Float16* bp = &wlt[(colt * 32 + rw) * 136 + kg * 8];
#pragma unroll
    for (int ks = 0; ks < 8; ++ks) {
      half8_t af = *(const half8_t*)&ap[ks * 16];
      half8_t bf = *(const half8_t*)&bp[ks * 16];
      C = __builtin_amdgcn_mfma_f32_32x32x16_f16(af, bf, C, 0, 0, 0);
    }
    colg = colt * 32 + rw;
    lbv = lb_s[colg];
    lbv_valid = 1;
  }
  __syncthreads();  // all vs reads done -> safe to overwrite as outbuf
  if (lbv_valid && colg < 40) {
    const int rowt = (t >> 6) >> 1;
    const int hi = (t & 63) >> 5;
#pragma unroll
    for (int q = 0; q < 16; ++q) {
      int row = (q & 3) + 8 * (q >> 2) + 4 * hi;  // C/D layout (m74/m101)
      outbuf[(rowt * 32 + row) * 68 + colg] = C[q] + lbv;
    }
  }
  __syncthreads();

  // softmax: node = t>>3, 5 classes per lane
  const int node = t >> 3;
  const int cg = (t & 7) * 5;
  const int n = n0 + node;
  float lg[5];
#pragma unroll
  for (int j = 0; j < 5; ++j) lg[j] = outbuf[node * 68 + cg + j];
  float mx = lg[0];
#pragma unroll
  for (int j = 1; j < 5; ++j) mx = fmaxf(mx, lg[j]);
  mx = fmaxf(mx, __shfl_xor(mx, 1));
  mx = fmaxf(mx, __shfl_xor(mx, 2));
  mx = fmaxf(mx, __shfl_xor(mx, 4));
  float ssum = 0.f;
#pragma unroll
  for (int j = 0; j < 5; ++j) ssum += expf(lg[j] - mx);
  ssum += __shfl_xor(ssum, 1);
  ssum += __shfl_xor(ssum, 2);
  ssum += __shfl_xor(ssum, 4);
  float lse = mx + logf(ssum);
  if (n < N_NODES) {
#pragma unroll
    for (int j = 0; j < 5; ++j) out[(size_t)n * 40 + cg + j] = lg[j] - lse;
  }
}

extern "C" void kernel_launch(void* const* d_in, const int* in_sizes, int n_in,
                              void* d_out, int out_size, void* d_ws, size_t ws_size,
                              hipStream_t stream) {
  const float* x    = (const float*)d_in[0];
  const int*   ei   = (const int*)d_in[1];
  const float* W1   = (const float*)d_in[2];
  const float* b1   = (const float*)d_in[3];
  const float* linW = (const float*)d_in[4];
  const float* linb = (const float*)d_in[5];
  float* out = (float*)d_out;
  char* ws = (char*)d_ws;

  int*           btot   = (int*)(ws + OFF_BTOT);
  unsigned char* hs8    = (unsigned char*)(ws + OFF_HS);
  __half*        Wt     = (__half*)(ws + OFF_WT);
  __half*        WlT    = (__half*)(ws + OFF_WLT);
  int*           ghist  = (int*)(ws + OFF_GHIST);
  int*           gchoff = (int*)(ws + OFF_GCHOFF);
  int*           dump   = (int*)(ws + OFF_DUMP);

  k_hist<<<NB_HIST + 17, 256, 0, stream>>>(ei, ghist, W1, Wt, linW, WlT);
  k_bucket_scan<<<NBUCK, 256, 0, stream>>>(ghist, gchoff, btot);
  k_bin<<<NB_BIN, 512, 0, stream>>>(ei, gchoff, dump);
  k_gemm1<<<NBUCK, 256, 0, stream>>>(x, Wt, dump, btot, hs8);
  k_aggfin<<<NBUCK, 512, 0, stream>>>(hs8, dump, btot, b1, WlT, linb, out);
}